// Round 1
// baseline (1869.127 us; speedup 1.0000x reference)
//
#include <hip/hip_runtime.h>

#define D 64

__global__ void k_deg(const int* __restrict__ dst, int* __restrict__ cnt, int E) {
    int e = blockIdx.x * 256 + threadIdx.x;
    if (e < E) atomicAdd(&cnt[dst[e]], 1);
}

__global__ void k_scan1(const int* __restrict__ cnt, int* __restrict__ part, int N) {
    __shared__ int s[256];
    int t = threadIdx.x;
    int i = blockIdx.x * 256 + t;
    s[t] = (i < N) ? cnt[i] : 0;
    __syncthreads();
    for (int d = 128; d > 0; d >>= 1) {
        if (t < d) s[t] += s[t + d];
        __syncthreads();
    }
    if (t == 0) part[blockIdx.x] = s[0];
}

__global__ void k_scan2(const int* __restrict__ part, int* __restrict__ boff, int nb) {
    __shared__ int s[256];
    int t = threadIdx.x;
    int v = (t < nb) ? part[t] : 0;
    s[t] = v;
    __syncthreads();
    for (int d = 1; d < 256; d <<= 1) {
        int add = (t >= d) ? s[t - d] : 0;
        __syncthreads();
        s[t] += add;
        __syncthreads();
    }
    if (t < nb) boff[t] = s[t] - v;  // exclusive prefix of block partials
}

__global__ void k_scan3(const int* __restrict__ cnt, const int* __restrict__ boff,
                        int* __restrict__ rp, int* __restrict__ cursor,
                        float* __restrict__ dinv, int N, int E) {
    __shared__ int s[256];
    int t = threadIdx.x;
    int i = blockIdx.x * 256 + t;
    int v = (i < N) ? cnt[i] : 0;
    s[t] = v;
    __syncthreads();
    for (int d = 1; d < 256; d <<= 1) {
        int add = (t >= d) ? s[t - d] : 0;
        __syncthreads();
        s[t] += add;
        __syncthreads();
    }
    if (i < N) {
        int excl = boff[blockIdx.x] + s[t] - v;
        rp[i] = excl;
        cursor[i] = excl;
        dinv[i] = 1.0f / sqrtf((float)v + 1.0f);  // deg includes self-loop (+1)
    }
    if (i == 0) rp[N] = E;
}

__global__ void k_fill(const int* __restrict__ src, const int* __restrict__ dst,
                       const float* __restrict__ dinv, int* __restrict__ cursor,
                       int2* __restrict__ pack, int E) {
    int e = blockIdx.x * 256 + threadIdx.x;
    if (e < E) {
        int s = src[e], d = dst[e];
        int pos = atomicAdd(&cursor[d], 1);
        int2 p;
        p.x = s;
        p.y = __float_as_int(dinv[s]);
        pack[pos] = p;
    }
}

// One wave per node; lane j owns feature j. z[n] = sum_{e:dst=n} x[src_e]*dinv[src_e]*dinv[n] + x[n]*dinv[n]^2
__global__ void k_agg(const float* __restrict__ x, const int* __restrict__ rp,
                      const int2* __restrict__ pack, const float* __restrict__ dinv,
                      float* __restrict__ z, int N) {
    int wid = (blockIdx.x * blockDim.x + threadIdx.x) >> 6;
    int j = threadIdx.x & 63;
    if (wid >= N) return;
    int n = wid;
    int s0 = rp[n], s1 = rp[n + 1];
    float dn = dinv[n];
    float acc = x[(long)n * D + j] * dn * dn;
    int e = s0;
    int2 p;
    if (e < s1) p = pack[e];
    while (e < s1) {
        int2 cur = p;
        ++e;
        if (e < s1) p = pack[e];  // prefetch next edge record while gathering current row
        acc = fmaf(x[(long)cur.x * D + j], __int_as_float(cur.y) * dn, acc);
    }
    z[(long)n * D + j] = acc;
}

// y[n] = z[n] @ W + b (optional relu). 64 nodes/block, 4 waves; lane j computes column j.
// W column j lives in 64 VGPRs (k-loop fully unrolled -> static indices); z tile transposed in LDS,
// read as wave-uniform float4 broadcasts (no bank conflicts).
template <int RELU>
__global__ void k_gemm(const float* __restrict__ z, const float* __restrict__ W,
                       const float* __restrict__ b, float* __restrict__ y, int N) {
    __shared__ float zT[D][68];  // pitch 68 floats = 272B: 16B-aligned rows for b128 reads
    int t = threadIdx.x;
    int n0 = blockIdx.x * 64;
    {
        int col4 = (t & 15) * 4;
        #pragma unroll
        for (int rr = 0; rr < 4; ++rr) {
            int row = (t >> 4) + rr * 16;
            int n = n0 + row;
            float4 v = make_float4(0.f, 0.f, 0.f, 0.f);
            if (n < N) v = *reinterpret_cast<const float4*>(&z[(long)n * D + col4]);
            zT[col4 + 0][row] = v.x;
            zT[col4 + 1][row] = v.y;
            zT[col4 + 2][row] = v.z;
            zT[col4 + 3][row] = v.w;
        }
    }
    int j = t & 63;
    int w = t >> 6;
    float Wc[D];
    #pragma unroll
    for (int k = 0; k < D; ++k) Wc[k] = W[k * D + j];  // coalesced: lanes read consecutive floats
    float bj = b[j];
    __syncthreads();
    #pragma unroll
    for (int q = 0; q < 4; ++q) {
        int nloc = w * 16 + q * 4;
        float ax = 0.f, ay = 0.f, az = 0.f, aw = 0.f;
        #pragma unroll
        for (int k = 0; k < D; ++k) {
            float4 zv = *reinterpret_cast<const float4*>(&zT[k][nloc]);  // wave-uniform broadcast
            ax = fmaf(zv.x, Wc[k], ax);
            ay = fmaf(zv.y, Wc[k], ay);
            az = fmaf(zv.z, Wc[k], az);
            aw = fmaf(zv.w, Wc[k], aw);
        }
        int n = n0 + nloc;
        float r;
        if (n + 0 < N) { r = ax + bj; if (RELU) r = fmaxf(r, 0.f); y[(long)(n + 0) * D + j] = r; }
        if (n + 1 < N) { r = ay + bj; if (RELU) r = fmaxf(r, 0.f); y[(long)(n + 1) * D + j] = r; }
        if (n + 2 < N) { r = az + bj; if (RELU) r = fmaxf(r, 0.f); y[(long)(n + 2) * D + j] = r; }
        if (n + 3 < N) { r = aw + bj; if (RELU) r = fmaxf(r, 0.f); y[(long)(n + 3) * D + j] = r; }
    }
}

extern "C" void kernel_launch(void* const* d_in, const int* in_sizes, int n_in,
                              void* d_out, int out_size, void* d_ws, size_t ws_size,
                              hipStream_t stream) {
    const float* x0  = (const float*)d_in[0];
    const int*   ei  = (const int*)d_in[1];
    const float* W1  = (const float*)d_in[2];
    const float* b1  = (const float*)d_in[3];
    const float* W2  = (const float*)d_in[4];
    const float* b2  = (const float*)d_in[5];
    const float* Wsc = (const float*)d_in[6];
    const float* bs  = (const float*)d_in[7];
    const float* Wmu = (const float*)d_in[8];
    const float* bmu = (const float*)d_in[9];
    const float* Wlv = (const float*)d_in[10];
    const float* blv = (const float*)d_in[11];

    int N = in_sizes[0] / D;
    int E = in_sizes[1] / 2;
    const int* src = ei;
    const int* dst = ei + E;

    char* ws = (char*)d_ws;
    size_t off = 0;
    auto alloc = [&](size_t bytes) {
        char* p = ws + off;
        off += (bytes + 255) & ~(size_t)255;
        return p;
    };
    int*   cnt    = (int*)alloc((size_t)N * 4);
    int*   rp     = (int*)alloc((size_t)(N + 1) * 4);
    int*   cursor = (int*)alloc((size_t)N * 4);
    float* dinv   = (float*)alloc((size_t)N * 4);
    int NB = (N + 255) / 256;  // 196 <= 256: single-block scan2 is valid
    int* part = (int*)alloc((size_t)NB * 4);
    int* boff = (int*)alloc((size_t)NB * 4);
    int2* pack = (int2*)alloc((size_t)E * 8);

    float* h    = (float*)d_out;                   // scratch; finally holds mu
    float* zbuf = (float*)d_out + (size_t)N * D;   // scratch; finally holds logvar

    hipMemsetAsync(cnt, 0, (size_t)N * 4, stream);
    int EB = (E + 255) / 256;
    k_deg  <<<EB, 256, 0, stream>>>(dst, cnt, E);
    k_scan1<<<NB, 256, 0, stream>>>(cnt, part, N);
    k_scan2<<<1, 256, 0, stream>>>(part, boff, NB);
    k_scan3<<<NB, 256, 0, stream>>>(cnt, boff, rp, cursor, dinv, N, E);
    k_fill <<<EB, 256, 0, stream>>>(src, dst, dinv, cursor, pack, E);

    int AB = (N + 3) / 4;
    int GB = (N + 63) / 64;
    // agg(x)@W == agg(x@W) by linearity; mu/logvar share the last aggregation.
    k_agg   <<<AB, 256, 0, stream>>>(x0, rp, pack, dinv, zbuf, N);
    k_gemm<0><<<GB, 256, 0, stream>>>(zbuf, W1, b1, h, N);
    k_agg   <<<AB, 256, 0, stream>>>(h, rp, pack, dinv, zbuf, N);
    k_gemm<0><<<GB, 256, 0, stream>>>(zbuf, W2, b2, h, N);
    k_agg   <<<AB, 256, 0, stream>>>(h, rp, pack, dinv, zbuf, N);
    k_gemm<1><<<GB, 256, 0, stream>>>(zbuf, Wsc, bs, h, N);
    k_agg   <<<AB, 256, 0, stream>>>(h, rp, pack, dinv, zbuf, N);
    k_gemm<0><<<GB, 256, 0, stream>>>(zbuf, Wmu, bmu, (float*)d_out, N);
    // in-place: each block stages its own 64 rows into LDS (behind __syncthreads) before writing them
    k_gemm<0><<<GB, 256, 0, stream>>>(zbuf, Wlv, blv, zbuf, N);
}

// Round 2
// 395.394 us; speedup vs baseline: 4.7273x; 4.7273x over previous
//
#include <hip/hip_runtime.h>

#define D 64

__global__ void k_deg(const int* __restrict__ dst, int* __restrict__ cnt, int E) {
    int e = blockIdx.x * 256 + threadIdx.x;
    if (e < E) atomicAdd(&cnt[dst[e]], 1);
}

__global__ void k_scan1(const int* __restrict__ cnt, int* __restrict__ part, int N) {
    __shared__ int s[256];
    int t = threadIdx.x;
    int i = blockIdx.x * 256 + t;
    s[t] = (i < N) ? cnt[i] : 0;
    __syncthreads();
    for (int d = 128; d > 0; d >>= 1) {
        if (t < d) s[t] += s[t + d];
        __syncthreads();
    }
    if (t == 0) part[blockIdx.x] = s[0];
}

__global__ void k_scan2(const int* __restrict__ part, int* __restrict__ boff, int nb) {
    __shared__ int s[256];
    int t = threadIdx.x;
    int v = (t < nb) ? part[t] : 0;
    s[t] = v;
    __syncthreads();
    for (int d = 1; d < 256; d <<= 1) {
        int add = (t >= d) ? s[t - d] : 0;
        __syncthreads();
        s[t] += add;
        __syncthreads();
    }
    if (t < nb) boff[t] = s[t] - v;  // exclusive prefix of block partials
}

__global__ void k_scan3(const int* __restrict__ cnt, const int* __restrict__ boff,
                        int* __restrict__ rp, int* __restrict__ cursor,
                        float* __restrict__ dinv, int N, int E) {
    __shared__ int s[256];
    int t = threadIdx.x;
    int i = blockIdx.x * 256 + t;
    int v = (i < N) ? cnt[i] : 0;
    s[t] = v;
    __syncthreads();
    for (int d = 1; d < 256; d <<= 1) {
        int add = (t >= d) ? s[t - d] : 0;
        __syncthreads();
        s[t] += add;
        __syncthreads();
    }
    if (i < N) {
        int excl = boff[blockIdx.x] + s[t] - v;
        rp[i] = excl;
        cursor[i] = excl;
        dinv[i] = 1.0f / sqrtf((float)v + 1.0f);  // deg includes self-loop (+1)
    }
    if (i == 0) rp[N] = E;
}

__global__ void k_fill(const int* __restrict__ src, const int* __restrict__ dst,
                       const float* __restrict__ dinv, int* __restrict__ cursor,
                       int2* __restrict__ pack, int E) {
    int e = blockIdx.x * 256 + threadIdx.x;
    if (e < E) {
        int s = src[e], d = dst[e];
        int pos = atomicAdd(&cursor[d], 1);
        int2 p;
        p.x = s;
        p.y = __float_as_int(dinv[s]);
        pack[pos] = p;
    }
}

// One wave per node; lane j owns feature j.
__global__ void k_agg(const float* __restrict__ x, const int* __restrict__ rp,
                      const int2* __restrict__ pack, const float* __restrict__ dinv,
                      float* __restrict__ z, int N) {
    int wid = (blockIdx.x * blockDim.x + threadIdx.x) >> 6;
    int j = threadIdx.x & 63;
    if (wid >= N) return;
    int n = wid;
    int s0 = rp[n], s1 = rp[n + 1];
    float dn = dinv[n];
    float acc = x[(size_t)n * D + j] * dn * dn;
    int e = s0;
    int2 p;
    if (e < s1) p = pack[e];
    while (e < s1) {
        int2 cur = p;
        ++e;
        if (e < s1) p = pack[e];  // prefetch next edge record while gathering current row
        acc = fmaf(x[(size_t)cur.x * D + j], __int_as_float(cur.y) * dn, acc);
    }
    z[(size_t)n * D + j] = acc;
}

// y = z @ W + b (optional relu). 64-row tile/block. W and transposed z both in LDS
// (NO per-thread arrays -> no scratch spill, which was the 345us/dispatch killer).
// Thread (ty,tx) owns a 4x4 C sub-tile; per k: 1 b128 from zT + 1 b128 from Wl + 16 fmac.
// Both LDS reads are 16B-aligned with few distinct addresses per wave -> broadcast, conflict-free.
template <int RELU>
__global__ __launch_bounds__(256) void k_gemm(const float* __restrict__ z,
                                              const float* __restrict__ W,
                                              const float* __restrict__ b,
                                              float* __restrict__ y, int N) {
    __shared__ float Wl[D * D];   // Wl[k*64 + col], row-major copy of W
    __shared__ float zT[D][68];   // zT[k][row] = z[n0+row][k]; pitch 68 keeps rows 16B-aligned
    int t = threadIdx.x;
    int n0 = blockIdx.x * 64;

    // stage W: 4096 floats, float4-coalesced, conflict-free LDS writes
    #pragma unroll
    for (int r = 0; r < 4; ++r) {
        float4 wv = reinterpret_cast<const float4*>(W)[t + 256 * r];
        *reinterpret_cast<float4*>(&Wl[(t + 256 * r) * 4]) = wv;
    }
    // stage z transposed: global reads perfectly coalesced (4KB contiguous per wave)
    {
        int col4 = (t & 15) * 4;
        int row_base = t >> 4;
        #pragma unroll
        for (int rr = 0; rr < 4; ++rr) {
            int row = row_base + rr * 16;
            int n = n0 + row;
            float4 v = make_float4(0.f, 0.f, 0.f, 0.f);
            if (n < N) v = *reinterpret_cast<const float4*>(&z[(size_t)n * D + col4]);
            zT[col4 + 0][row] = v.x;
            zT[col4 + 1][row] = v.y;
            zT[col4 + 2][row] = v.z;
            zT[col4 + 3][row] = v.w;
        }
    }
    int tx = t & 15;        // output column group
    int ty = t >> 4;        // output row group
    int col4 = tx * 4;
    int row4 = ty * 4;
    __syncthreads();

    float4 a0 = make_float4(0.f, 0.f, 0.f, 0.f);
    float4 a1 = make_float4(0.f, 0.f, 0.f, 0.f);
    float4 a2 = make_float4(0.f, 0.f, 0.f, 0.f);
    float4 a3 = make_float4(0.f, 0.f, 0.f, 0.f);
    #pragma unroll 16
    for (int k = 0; k < D; ++k) {
        float4 zv = *reinterpret_cast<const float4*>(&zT[k][row4]);
        float4 wv = *reinterpret_cast<const float4*>(&Wl[k * D + col4]);
        a0.x = fmaf(zv.x, wv.x, a0.x); a0.y = fmaf(zv.x, wv.y, a0.y);
        a0.z = fmaf(zv.x, wv.z, a0.z); a0.w = fmaf(zv.x, wv.w, a0.w);
        a1.x = fmaf(zv.y, wv.x, a1.x); a1.y = fmaf(zv.y, wv.y, a1.y);
        a1.z = fmaf(zv.y, wv.z, a1.z); a1.w = fmaf(zv.y, wv.w, a1.w);
        a2.x = fmaf(zv.z, wv.x, a2.x); a2.y = fmaf(zv.z, wv.y, a2.y);
        a2.z = fmaf(zv.z, wv.z, a2.z); a2.w = fmaf(zv.z, wv.w, a2.w);
        a3.x = fmaf(zv.w, wv.x, a3.x); a3.y = fmaf(zv.w, wv.y, a3.y);
        a3.z = fmaf(zv.w, wv.z, a3.z); a3.w = fmaf(zv.w, wv.w, a3.w);
    }
    float4 bv = *reinterpret_cast<const float4*>(&b[col4]);
    float4 r0 = make_float4(a0.x + bv.x, a0.y + bv.y, a0.z + bv.z, a0.w + bv.w);
    float4 r1 = make_float4(a1.x + bv.x, a1.y + bv.y, a1.z + bv.z, a1.w + bv.w);
    float4 r2 = make_float4(a2.x + bv.x, a2.y + bv.y, a2.z + bv.z, a2.w + bv.w);
    float4 r3 = make_float4(a3.x + bv.x, a3.y + bv.y, a3.z + bv.z, a3.w + bv.w);
    if (RELU) {
        r0.x = fmaxf(r0.x, 0.f); r0.y = fmaxf(r0.y, 0.f); r0.z = fmaxf(r0.z, 0.f); r0.w = fmaxf(r0.w, 0.f);
        r1.x = fmaxf(r1.x, 0.f); r1.y = fmaxf(r1.y, 0.f); r1.z = fmaxf(r1.z, 0.f); r1.w = fmaxf(r1.w, 0.f);
        r2.x = fmaxf(r2.x, 0.f); r2.y = fmaxf(r2.y, 0.f); r2.z = fmaxf(r2.z, 0.f); r2.w = fmaxf(r2.w, 0.f);
        r3.x = fmaxf(r3.x, 0.f); r3.y = fmaxf(r3.y, 0.f); r3.z = fmaxf(r3.z, 0.f); r3.w = fmaxf(r3.w, 0.f);
    }
    int n = n0 + row4;
    if (n + 0 < N) *reinterpret_cast<float4*>(&y[(size_t)(n + 0) * D + col4]) = r0;
    if (n + 1 < N) *reinterpret_cast<float4*>(&y[(size_t)(n + 1) * D + col4]) = r1;
    if (n + 2 < N) *reinterpret_cast<float4*>(&y[(size_t)(n + 2) * D + col4]) = r2;
    if (n + 3 < N) *reinterpret_cast<float4*>(&y[(size_t)(n + 3) * D + col4]) = r3;
}

extern "C" void kernel_launch(void* const* d_in, const int* in_sizes, int n_in,
                              void* d_out, int out_size, void* d_ws, size_t ws_size,
                              hipStream_t stream) {
    const float* x0  = (const float*)d_in[0];
    const int*   ei  = (const int*)d_in[1];
    const float* W1  = (const float*)d_in[2];
    const float* b1  = (const float*)d_in[3];
    const float* W2  = (const float*)d_in[4];
    const float* b2  = (const float*)d_in[5];
    const float* Wsc = (const float*)d_in[6];
    const float* bs  = (const float*)d_in[7];
    const float* Wmu = (const float*)d_in[8];
    const float* bmu = (const float*)d_in[9];
    const float* Wlv = (const float*)d_in[10];
    const float* blv = (const float*)d_in[11];

    int N = in_sizes[0] / D;
    int E = in_sizes[1] / 2;
    const int* src = ei;
    const int* dst = ei + E;

    char* ws = (char*)d_ws;
    size_t off = 0;
    auto alloc = [&](size_t bytes) {
        char* p = ws + off;
        off += (bytes + 255) & ~(size_t)255;
        return p;
    };
    int*   cnt    = (int*)alloc((size_t)N * 4);
    int*   rp     = (int*)alloc((size_t)(N + 1) * 4);
    int*   cursor = (int*)alloc((size_t)N * 4);
    float* dinv   = (float*)alloc((size_t)N * 4);
    int NB = (N + 255) / 256;  // 196 <= 256: single-block scan2 is valid
    int* part = (int*)alloc((size_t)NB * 4);
    int* boff = (int*)alloc((size_t)NB * 4);
    int2* pack = (int2*)alloc((size_t)E * 8);

    float* h    = (float*)d_out;                   // scratch; finally holds mu
    float* zbuf = (float*)d_out + (size_t)N * D;   // scratch; finally holds logvar

    hipMemsetAsync(cnt, 0, (size_t)N * 4, stream);
    int EB = (E + 255) / 256;
    k_deg  <<<EB, 256, 0, stream>>>(dst, cnt, E);
    k_scan1<<<NB, 256, 0, stream>>>(cnt, part, N);
    k_scan2<<<1, 256, 0, stream>>>(part, boff, NB);
    k_scan3<<<NB, 256, 0, stream>>>(cnt, boff, rp, cursor, dinv, N, E);
    k_fill <<<EB, 256, 0, stream>>>(src, dst, dinv, cursor, pack, E);

    int AB = (N + 3) / 4;
    int GB = (N + 63) / 64;
    // agg(x)@W == agg(x@W) by linearity; mu/logvar share the last aggregation.
    k_agg   <<<AB, 256, 0, stream>>>(x0, rp, pack, dinv, zbuf, N);
    k_gemm<0><<<GB, 256, 0, stream>>>(zbuf, W1, b1, h, N);
    k_agg   <<<AB, 256, 0, stream>>>(h, rp, pack, dinv, zbuf, N);
    k_gemm<0><<<GB, 256, 0, stream>>>(zbuf, W2, b2, h, N);
    k_agg   <<<AB, 256, 0, stream>>>(h, rp, pack, dinv, zbuf, N);
    k_gemm<1><<<GB, 256, 0, stream>>>(zbuf, Wsc, bs, h, N);
    k_agg   <<<AB, 256, 0, stream>>>(h, rp, pack, dinv, zbuf, N);
    k_gemm<0><<<GB, 256, 0, stream>>>(zbuf, Wmu, bmu, (float*)d_out, N);
    // in-place: each block stages its own 64 rows into LDS (behind __syncthreads) before writing them
    k_gemm<0><<<GB, 256, 0, stream>>>(zbuf, Wlv, blv, zbuf, N);
}

// Round 3
// 279.343 us; speedup vs baseline: 6.6912x; 1.4154x over previous
//
#include <hip/hip_runtime.h>

#define D 64

// rank[e] = this edge's position within its dst node's list (counting-sort rank).
__global__ void k_deg(const int* __restrict__ dst, int* __restrict__ cnt,
                      int* __restrict__ rank, int E) {
    int e = blockIdx.x * 256 + threadIdx.x;
    if (e < E) rank[e] = atomicAdd(&cnt[dst[e]], 1);
}

__global__ void k_scan1(const int* __restrict__ cnt, int* __restrict__ part, int N) {
    __shared__ int s[256];
    int t = threadIdx.x;
    int i = blockIdx.x * 256 + t;
    s[t] = (i < N) ? cnt[i] : 0;
    __syncthreads();
    for (int d = 128; d > 0; d >>= 1) {
        if (t < d) s[t] += s[t + d];
        __syncthreads();
    }
    if (t == 0) part[blockIdx.x] = s[0];
}

__global__ void k_scan2(const int* __restrict__ part, int* __restrict__ boff, int nb) {
    __shared__ int s[256];
    int t = threadIdx.x;
    int v = (t < nb) ? part[t] : 0;
    s[t] = v;
    __syncthreads();
    for (int d = 1; d < 256; d <<= 1) {
        int add = (t >= d) ? s[t - d] : 0;
        __syncthreads();
        s[t] += add;
        __syncthreads();
    }
    if (t < nb) boff[t] = s[t] - v;  // exclusive prefix of block partials
}

__global__ void k_scan3(const int* __restrict__ cnt, const int* __restrict__ boff,
                        int* __restrict__ rp, float* __restrict__ dinv, int N, int E) {
    __shared__ int s[256];
    int t = threadIdx.x;
    int i = blockIdx.x * 256 + t;
    int v = (i < N) ? cnt[i] : 0;
    s[t] = v;
    __syncthreads();
    for (int d = 1; d < 256; d <<= 1) {
        int add = (t >= d) ? s[t - d] : 0;
        __syncthreads();
        s[t] += add;
        __syncthreads();
    }
    if (i < N) {
        int excl = boff[blockIdx.x] + s[t] - v;
        rp[i] = excl;
        dinv[i] = 1.0f / sqrtf((float)v + 1.0f);  // deg includes self-loop (+1)
    }
    if (i == 0) rp[N] = E;
}

// Atomic-free scatter: position known from rank. 4B payload (src only).
__global__ void k_fill(const int* __restrict__ src, const int* __restrict__ dst,
                       const int* __restrict__ rank, const int* __restrict__ rp,
                       int* __restrict__ pack, int E) {
    int e = blockIdx.x * 256 + threadIdx.x;
    if (e < E) pack[rp[dst[e]] + rank[e]] = src[e];
}

// One wave per node; lane j owns feature j. 8-wide unrolled edge loop:
// 8 independent x-row gathers in flight per wave (was 1 -> latency-bound).
__global__ void k_agg(const float* __restrict__ x, const int* __restrict__ rp,
                      const int* __restrict__ pack, const float* __restrict__ dinv,
                      float* __restrict__ z, int N) {
    int wid = (blockIdx.x * blockDim.x + threadIdx.x) >> 6;
    int j = threadIdx.x & 63;
    if (wid >= N) return;
    int n = wid;
    int s0 = rp[n], s1 = rp[n + 1];
    float dn = dinv[n];
    float a0 = x[(size_t)n * D + j] * dn * dn;
    float a1 = 0.f, a2 = 0.f, a3 = 0.f;
    int e = s0;
    for (; e + 8 <= s1; e += 8) {
        int i0 = pack[e + 0], i1 = pack[e + 1], i2 = pack[e + 2], i3 = pack[e + 3];
        int i4 = pack[e + 4], i5 = pack[e + 5], i6 = pack[e + 6], i7 = pack[e + 7];
        float c0 = dinv[i0], c1 = dinv[i1], c2 = dinv[i2], c3 = dinv[i3];
        float c4 = dinv[i4], c5 = dinv[i5], c6 = dinv[i6], c7 = dinv[i7];
        float v0 = x[(size_t)i0 * D + j], v1 = x[(size_t)i1 * D + j];
        float v2 = x[(size_t)i2 * D + j], v3 = x[(size_t)i3 * D + j];
        float v4 = x[(size_t)i4 * D + j], v5 = x[(size_t)i5 * D + j];
        float v6 = x[(size_t)i6 * D + j], v7 = x[(size_t)i7 * D + j];
        a0 = fmaf(v0, c0 * dn, a0);
        a1 = fmaf(v1, c1 * dn, a1);
        a2 = fmaf(v2, c2 * dn, a2);
        a3 = fmaf(v3, c3 * dn, a3);
        a0 = fmaf(v4, c4 * dn, a0);
        a1 = fmaf(v5, c5 * dn, a1);
        a2 = fmaf(v6, c6 * dn, a2);
        a3 = fmaf(v7, c7 * dn, a3);
    }
    for (; e < s1; ++e) {
        int i0 = pack[e];
        a0 = fmaf(x[(size_t)i0 * D + j], dinv[i0] * dn, a0);
    }
    z[(size_t)n * D + j] = (a0 + a1) + (a2 + a3);
}

// y = z @ W + b (optional relu). 64-row tile/block, no per-thread arrays.
template <int RELU>
__global__ __launch_bounds__(256) void k_gemm(const float* __restrict__ z,
                                              const float* __restrict__ W,
                                              const float* __restrict__ b,
                                              float* __restrict__ y, int N) {
    __shared__ float Wl[D * D];   // Wl[k*64 + col]
    __shared__ float zT[D][68];   // zT[k][row]; pitch 68 keeps rows 16B-aligned
    int t = threadIdx.x;
    int n0 = blockIdx.x * 64;

    #pragma unroll
    for (int r = 0; r < 4; ++r) {
        float4 wv = reinterpret_cast<const float4*>(W)[t + 256 * r];
        *reinterpret_cast<float4*>(&Wl[(t + 256 * r) * 4]) = wv;
    }
    {
        int col4 = (t & 15) * 4;
        int row_base = t >> 4;
        #pragma unroll
        for (int rr = 0; rr < 4; ++rr) {
            int row = row_base + rr * 16;
            int n = n0 + row;
            float4 v = make_float4(0.f, 0.f, 0.f, 0.f);
            if (n < N) v = *reinterpret_cast<const float4*>(&z[(size_t)n * D + col4]);
            zT[col4 + 0][row] = v.x;
            zT[col4 + 1][row] = v.y;
            zT[col4 + 2][row] = v.z;
            zT[col4 + 3][row] = v.w;
        }
    }
    int col4 = (t & 15) * 4;
    int row4 = (t >> 4) * 4;
    __syncthreads();

    float4 a0 = make_float4(0.f, 0.f, 0.f, 0.f);
    float4 a1 = make_float4(0.f, 0.f, 0.f, 0.f);
    float4 a2 = make_float4(0.f, 0.f, 0.f, 0.f);
    float4 a3 = make_float4(0.f, 0.f, 0.f, 0.f);
    #pragma unroll 16
    for (int k = 0; k < D; ++k) {
        float4 zv = *reinterpret_cast<const float4*>(&zT[k][row4]);
        float4 wv = *reinterpret_cast<const float4*>(&Wl[k * D + col4]);
        a0.x = fmaf(zv.x, wv.x, a0.x); a0.y = fmaf(zv.x, wv.y, a0.y);
        a0.z = fmaf(zv.x, wv.z, a0.z); a0.w = fmaf(zv.x, wv.w, a0.w);
        a1.x = fmaf(zv.y, wv.x, a1.x); a1.y = fmaf(zv.y, wv.y, a1.y);
        a1.z = fmaf(zv.y, wv.z, a1.z); a1.w = fmaf(zv.y, wv.w, a1.w);
        a2.x = fmaf(zv.z, wv.x, a2.x); a2.y = fmaf(zv.z, wv.y, a2.y);
        a2.z = fmaf(zv.z, wv.z, a2.z); a2.w = fmaf(zv.z, wv.w, a2.w);
        a3.x = fmaf(zv.w, wv.x, a3.x); a3.y = fmaf(zv.w, wv.y, a3.y);
        a3.z = fmaf(zv.w, wv.z, a3.z); a3.w = fmaf(zv.w, wv.w, a3.w);
    }
    float4 bv = *reinterpret_cast<const float4*>(&b[col4]);
    float4 r0 = make_float4(a0.x + bv.x, a0.y + bv.y, a0.z + bv.z, a0.w + bv.w);
    float4 r1 = make_float4(a1.x + bv.x, a1.y + bv.y, a1.z + bv.z, a1.w + bv.w);
    float4 r2 = make_float4(a2.x + bv.x, a2.y + bv.y, a2.z + bv.z, a2.w + bv.w);
    float4 r3 = make_float4(a3.x + bv.x, a3.y + bv.y, a3.z + bv.z, a3.w + bv.w);
    if (RELU) {
        r0.x = fmaxf(r0.x, 0.f); r0.y = fmaxf(r0.y, 0.f); r0.z = fmaxf(r0.z, 0.f); r0.w = fmaxf(r0.w, 0.f);
        r1.x = fmaxf(r1.x, 0.f); r1.y = fmaxf(r1.y, 0.f); r1.z = fmaxf(r1.z, 0.f); r1.w = fmaxf(r1.w, 0.f);
        r2.x = fmaxf(r2.x, 0.f); r2.y = fmaxf(r2.y, 0.f); r2.z = fmaxf(r2.z, 0.f); r2.w = fmaxf(r2.w, 0.f);
        r3.x = fmaxf(r3.x, 0.f); r3.y = fmaxf(r3.y, 0.f); r3.z = fmaxf(r3.z, 0.f); r3.w = fmaxf(r3.w, 0.f);
    }
    int n = n0 + row4;
    if (n + 0 < N) *reinterpret_cast<float4*>(&y[(size_t)(n + 0) * D + col4]) = r0;
    if (n + 1 < N) *reinterpret_cast<float4*>(&y[(size_t)(n + 1) * D + col4]) = r1;
    if (n + 2 < N) *reinterpret_cast<float4*>(&y[(size_t)(n + 2) * D + col4]) = r2;
    if (n + 3 < N) *reinterpret_cast<float4*>(&y[(size_t)(n + 3) * D + col4]) = r3;
}

// Dual GEMM: reads z once, produces ya = z@Wa+ba and yb = z@Wb+bb.
// In-place safe for yb==z: block stages its own rows in LDS behind the barrier.
__global__ __launch_bounds__(256) void k_gemm_dual(const float* __restrict__ z,
                                                   const float* __restrict__ Wa,
                                                   const float* __restrict__ ba,
                                                   const float* __restrict__ Wb,
                                                   const float* __restrict__ bb,
                                                   float* __restrict__ ya,
                                                   float* __restrict__ yb, int N) {
    __shared__ float Wla[D * D];
    __shared__ float Wlb[D * D];
    __shared__ float zT[D][68];
    int t = threadIdx.x;
    int n0 = blockIdx.x * 64;

    #pragma unroll
    for (int r = 0; r < 4; ++r) {
        float4 wv = reinterpret_cast<const float4*>(Wa)[t + 256 * r];
        *reinterpret_cast<float4*>(&Wla[(t + 256 * r) * 4]) = wv;
        float4 wv2 = reinterpret_cast<const float4*>(Wb)[t + 256 * r];
        *reinterpret_cast<float4*>(&Wlb[(t + 256 * r) * 4]) = wv2;
    }
    {
        int col4 = (t & 15) * 4;
        int row_base = t >> 4;
        #pragma unroll
        for (int rr = 0; rr < 4; ++rr) {
            int row = row_base + rr * 16;
            int n = n0 + row;
            float4 v = make_float4(0.f, 0.f, 0.f, 0.f);
            if (n < N) v = *reinterpret_cast<const float4*>(&z[(size_t)n * D + col4]);
            zT[col4 + 0][row] = v.x;
            zT[col4 + 1][row] = v.y;
            zT[col4 + 2][row] = v.z;
            zT[col4 + 3][row] = v.w;
        }
    }
    int col4 = (t & 15) * 4;
    int row4 = (t >> 4) * 4;
    __syncthreads();

    float4 a0 = make_float4(0.f, 0.f, 0.f, 0.f), a1 = a0, a2 = a0, a3 = a0;
    float4 c0 = a0, c1 = a0, c2 = a0, c3 = a0;
    #pragma unroll 8
    for (int k = 0; k < D; ++k) {
        float4 zv = *reinterpret_cast<const float4*>(&zT[k][row4]);
        float4 wv = *reinterpret_cast<const float4*>(&Wla[k * D + col4]);
        float4 uv = *reinterpret_cast<const float4*>(&Wlb[k * D + col4]);
        a0.x = fmaf(zv.x, wv.x, a0.x); a0.y = fmaf(zv.x, wv.y, a0.y);
        a0.z = fmaf(zv.x, wv.z, a0.z); a0.w = fmaf(zv.x, wv.w, a0.w);
        a1.x = fmaf(zv.y, wv.x, a1.x); a1.y = fmaf(zv.y, wv.y, a1.y);
        a1.z = fmaf(zv.y, wv.z, a1.z); a1.w = fmaf(zv.y, wv.w, a1.w);
        a2.x = fmaf(zv.z, wv.x, a2.x); a2.y = fmaf(zv.z, wv.y, a2.y);
        a2.z = fmaf(zv.z, wv.z, a2.z); a2.w = fmaf(zv.z, wv.w, a2.w);
        a3.x = fmaf(zv.w, wv.x, a3.x); a3.y = fmaf(zv.w, wv.y, a3.y);
        a3.z = fmaf(zv.w, wv.z, a3.z); a3.w = fmaf(zv.w, wv.w, a3.w);
        c0.x = fmaf(zv.x, uv.x, c0.x); c0.y = fmaf(zv.x, uv.y, c0.y);
        c0.z = fmaf(zv.x, uv.z, c0.z); c0.w = fmaf(zv.x, uv.w, c0.w);
        c1.x = fmaf(zv.y, uv.x, c1.x); c1.y = fmaf(zv.y, uv.y, c1.y);
        c1.z = fmaf(zv.y, uv.z, c1.z); c1.w = fmaf(zv.y, uv.w, c1.w);
        c2.x = fmaf(zv.z, uv.x, c2.x); c2.y = fmaf(zv.z, uv.y, c2.y);
        c2.z = fmaf(zv.z, uv.z, c2.z); c2.w = fmaf(zv.z, uv.w, c2.w);
        c3.x = fmaf(zv.w, uv.x, c3.x); c3.y = fmaf(zv.w, uv.y, c3.y);
        c3.z = fmaf(zv.w, uv.z, c3.z); c3.w = fmaf(zv.w, uv.w, c3.w);
    }
    float4 bav = *reinterpret_cast<const float4*>(&ba[col4]);
    float4 bbv = *reinterpret_cast<const float4*>(&bb[col4]);
    int n = n0 + row4;
    if (n + 0 < N) {
        *reinterpret_cast<float4*>(&ya[(size_t)(n + 0) * D + col4]) =
            make_float4(a0.x + bav.x, a0.y + bav.y, a0.z + bav.z, a0.w + bav.w);
        *reinterpret_cast<float4*>(&yb[(size_t)(n + 0) * D + col4]) =
            make_float4(c0.x + bbv.x, c0.y + bbv.y, c0.z + bbv.z, c0.w + bbv.w);
    }
    if (n + 1 < N) {
        *reinterpret_cast<float4*>(&ya[(size_t)(n + 1) * D + col4]) =
            make_float4(a1.x + bav.x, a1.y + bav.y, a1.z + bav.z, a1.w + bav.w);
        *reinterpret_cast<float4*>(&yb[(size_t)(n + 1) * D + col4]) =
            make_float4(c1.x + bbv.x, c1.y + bbv.y, c1.z + bbv.z, c1.w + bbv.w);
    }
    if (n + 2 < N) {
        *reinterpret_cast<float4*>(&ya[(size_t)(n + 2) * D + col4]) =
            make_float4(a2.x + bav.x, a2.y + bav.y, a2.z + bav.z, a2.w + bav.w);
        *reinterpret_cast<float4*>(&yb[(size_t)(n + 2) * D + col4]) =
            make_float4(c2.x + bbv.x, c2.y + bbv.y, c2.z + bbv.z, c2.w + bbv.w);
    }
    if (n + 3 < N) {
        *reinterpret_cast<float4*>(&ya[(size_t)(n + 3) * D + col4]) =
            make_float4(a3.x + bav.x, a3.y + bav.y, a3.z + bav.z, a3.w + bav.w);
        *reinterpret_cast<float4*>(&yb[(size_t)(n + 3) * D + col4]) =
            make_float4(c3.x + bbv.x, c3.y + bbv.y, c3.z + bbv.z, c3.w + bbv.w);
    }
}

extern "C" void kernel_launch(void* const* d_in, const int* in_sizes, int n_in,
                              void* d_out, int out_size, void* d_ws, size_t ws_size,
                              hipStream_t stream) {
    const float* x0  = (const float*)d_in[0];
    const int*   ei  = (const int*)d_in[1];
    const float* W1  = (const float*)d_in[2];
    const float* b1  = (const float*)d_in[3];
    const float* W2  = (const float*)d_in[4];
    const float* b2  = (const float*)d_in[5];
    const float* Wsc = (const float*)d_in[6];
    const float* bs  = (const float*)d_in[7];
    const float* Wmu = (const float*)d_in[8];
    const float* bmu = (const float*)d_in[9];
    const float* Wlv = (const float*)d_in[10];
    const float* blv = (const float*)d_in[11];

    int N = in_sizes[0] / D;
    int E = in_sizes[1] / 2;
    const int* src = ei;
    const int* dst = ei + E;

    char* ws = (char*)d_ws;
    size_t off = 0;
    auto alloc = [&](size_t bytes) {
        char* p = ws + off;
        off += (bytes + 255) & ~(size_t)255;
        return p;
    };
    int*   cnt  = (int*)alloc((size_t)N * 4);
    int*   rp   = (int*)alloc((size_t)(N + 1) * 4);
    float* dinv = (float*)alloc((size_t)N * 4);
    int NB = (N + 255) / 256;  // 196 <= 256: single-block scan2 is valid
    int* part = (int*)alloc((size_t)NB * 4);
    int* boff = (int*)alloc((size_t)NB * 4);
    int* rank = (int*)alloc((size_t)E * 4);
    int* pack = (int*)alloc((size_t)E * 4);

    float* h    = (float*)d_out;                   // scratch; finally holds mu
    float* zbuf = (float*)d_out + (size_t)N * D;   // scratch; finally holds logvar

    hipMemsetAsync(cnt, 0, (size_t)N * 4, stream);
    int EB = (E + 255) / 256;
    k_deg  <<<EB, 256, 0, stream>>>(dst, cnt, rank, E);
    k_scan1<<<NB, 256, 0, stream>>>(cnt, part, N);
    k_scan2<<<1, 256, 0, stream>>>(part, boff, NB);
    k_scan3<<<NB, 256, 0, stream>>>(cnt, boff, rp, dinv, N, E);
    k_fill <<<EB, 256, 0, stream>>>(src, dst, rank, rp, pack, E);

    int AB = (N + 3) / 4;
    int GB = (N + 63) / 64;
    // agg(x)@W == agg(x@W) by linearity; mu/logvar share the last aggregation.
    k_agg   <<<AB, 256, 0, stream>>>(x0, rp, pack, dinv, zbuf, N);
    k_gemm<0><<<GB, 256, 0, stream>>>(zbuf, W1, b1, h, N);
    k_agg   <<<AB, 256, 0, stream>>>(h, rp, pack, dinv, zbuf, N);
    k_gemm<0><<<GB, 256, 0, stream>>>(zbuf, W2, b2, h, N);
    k_agg   <<<AB, 256, 0, stream>>>(h, rp, pack, dinv, zbuf, N);
    k_gemm<1><<<GB, 256, 0, stream>>>(zbuf, Wsc, bs, h, N);
    k_agg   <<<AB, 256, 0, stream>>>(h, rp, pack, dinv, zbuf, N);
    // mu -> d_out first half; logvar in-place over zbuf (second half)
    k_gemm_dual<<<GB, 256, 0, stream>>>(zbuf, Wmu, bmu, Wlv, blv, (float*)d_out, zbuf, N);
}

// Round 4
// 244.123 us; speedup vs baseline: 7.6565x; 1.1443x over previous
//
#include <hip/hip_runtime.h>

#define D 64

__global__ void k_zero(int* __restrict__ p, int n) {
    int i = blockIdx.x * 256 + threadIdx.x;
    if (i < n) p[i] = 0;
}

// rank[e] = this edge's position within its dst node's list (counting-sort rank).
__global__ void k_deg(const int* __restrict__ dst, int* __restrict__ cnt,
                      int* __restrict__ rank, int E) {
    int e = blockIdx.x * 256 + threadIdx.x;
    if (e < E) rank[e] = atomicAdd(&cnt[dst[e]], 1);
}

__global__ void k_scan1(const int* __restrict__ cnt, int* __restrict__ part, int N) {
    __shared__ int s[256];
    int t = threadIdx.x;
    int i = blockIdx.x * 256 + t;
    s[t] = (i < N) ? cnt[i] : 0;
    __syncthreads();
    for (int d = 128; d > 0; d >>= 1) {
        if (t < d) s[t] += s[t + d];
        __syncthreads();
    }
    if (t == 0) part[blockIdx.x] = s[0];
}

__global__ void k_scan2(const int* __restrict__ part, int* __restrict__ boff, int nb) {
    __shared__ int s[256];
    int t = threadIdx.x;
    int v = (t < nb) ? part[t] : 0;
    s[t] = v;
    __syncthreads();
    for (int d = 1; d < 256; d <<= 1) {
        int add = (t >= d) ? s[t - d] : 0;
        __syncthreads();
        s[t] += add;
        __syncthreads();
    }
    if (t < nb) boff[t] = s[t] - v;  // exclusive prefix of block partials
}

__global__ void k_scan3(const int* __restrict__ cnt, const int* __restrict__ boff,
                        int* __restrict__ rp, float* __restrict__ dinv, int N, int E) {
    __shared__ int s[256];
    int t = threadIdx.x;
    int i = blockIdx.x * 256 + t;
    int v = (i < N) ? cnt[i] : 0;
    s[t] = v;
    __syncthreads();
    for (int d = 1; d < 256; d <<= 1) {
        int add = (t >= d) ? s[t - d] : 0;
        __syncthreads();
        s[t] += add;
        __syncthreads();
    }
    if (i < N) {
        int excl = boff[blockIdx.x] + s[t] - v;
        rp[i] = excl;
        dinv[i] = 1.0f / sqrtf((float)v + 1.0f);  // deg includes self-loop (+1)
    }
    if (i == 0) rp[N] = E;
}

// Atomic-free scatter: position known from rank. 4B payload (src only).
__global__ void k_fill(const int* __restrict__ src, const int* __restrict__ dst,
                       const int* __restrict__ rank, const int* __restrict__ rp,
                       int* __restrict__ pack, int E) {
    int e = blockIdx.x * 256 + threadIdx.x;
    if (e < E) pack[rp[dst[e]] + rank[e]] = src[e];
}

// 4 nodes per wave, float4 per lane (16 lanes x 16B = one 256B row per group).
// 8-deep unroll -> up to 32 row-gathers in flight per wave (was 8).
__global__ void k_agg(const float* __restrict__ x, const int* __restrict__ rp,
                      const int* __restrict__ pack, const float* __restrict__ dinv,
                      float* __restrict__ z, int N) {
    int gt = blockIdx.x * blockDim.x + threadIdx.x;
    int wid = gt >> 6;
    int lane = threadIdx.x & 63;
    int g = lane >> 4;      // node group within wave (0..3)
    int l16 = lane & 15;    // lane within group: owns features 4*l16..4*l16+3
    int n = wid * 4 + g;
    if (n >= N) return;
    int s0 = rp[n], s1 = rp[n + 1];
    float dn = dinv[n];
    const float4* x4 = reinterpret_cast<const float4*>(x);
    float4 sv = x4[(size_t)n * 16 + l16];
    float dnn = dn * dn;
    float ax = sv.x * dnn, ay = sv.y * dnn, az = sv.z * dnn, aw = sv.w * dnn;
    float bx = 0.f, by = 0.f, bz = 0.f, bw = 0.f;
    int e = s0;
    for (; e + 8 <= s1; e += 8) {
        int i0 = pack[e + 0], i1 = pack[e + 1], i2 = pack[e + 2], i3 = pack[e + 3];
        int i4 = pack[e + 4], i5 = pack[e + 5], i6 = pack[e + 6], i7 = pack[e + 7];
        float c0 = dinv[i0] * dn, c1 = dinv[i1] * dn, c2 = dinv[i2] * dn, c3 = dinv[i3] * dn;
        float c4 = dinv[i4] * dn, c5 = dinv[i5] * dn, c6 = dinv[i6] * dn, c7 = dinv[i7] * dn;
        float4 v0 = x4[(size_t)i0 * 16 + l16];
        float4 v1 = x4[(size_t)i1 * 16 + l16];
        float4 v2 = x4[(size_t)i2 * 16 + l16];
        float4 v3 = x4[(size_t)i3 * 16 + l16];
        float4 v4 = x4[(size_t)i4 * 16 + l16];
        float4 v5 = x4[(size_t)i5 * 16 + l16];
        float4 v6 = x4[(size_t)i6 * 16 + l16];
        float4 v7 = x4[(size_t)i7 * 16 + l16];
        ax = fmaf(v0.x, c0, ax); ay = fmaf(v0.y, c0, ay); az = fmaf(v0.z, c0, az); aw = fmaf(v0.w, c0, aw);
        bx = fmaf(v1.x, c1, bx); by = fmaf(v1.y, c1, by); bz = fmaf(v1.z, c1, bz); bw = fmaf(v1.w, c1, bw);
        ax = fmaf(v2.x, c2, ax); ay = fmaf(v2.y, c2, ay); az = fmaf(v2.z, c2, az); aw = fmaf(v2.w, c2, aw);
        bx = fmaf(v3.x, c3, bx); by = fmaf(v3.y, c3, by); bz = fmaf(v3.z, c3, bz); bw = fmaf(v3.w, c3, bw);
        ax = fmaf(v4.x, c4, ax); ay = fmaf(v4.y, c4, ay); az = fmaf(v4.z, c4, az); aw = fmaf(v4.w, c4, aw);
        bx = fmaf(v5.x, c5, bx); by = fmaf(v5.y, c5, by); bz = fmaf(v5.z, c5, bz); bw = fmaf(v5.w, c5, bw);
        ax = fmaf(v6.x, c6, ax); ay = fmaf(v6.y, c6, ay); az = fmaf(v6.z, c6, az); aw = fmaf(v6.w, c6, aw);
        bx = fmaf(v7.x, c7, bx); by = fmaf(v7.y, c7, by); bz = fmaf(v7.z, c7, bz); bw = fmaf(v7.w, c7, bw);
    }
    for (; e + 2 <= s1; e += 2) {
        int i0 = pack[e], i1 = pack[e + 1];
        float c0 = dinv[i0] * dn, c1 = dinv[i1] * dn;
        float4 v0 = x4[(size_t)i0 * 16 + l16];
        float4 v1 = x4[(size_t)i1 * 16 + l16];
        ax = fmaf(v0.x, c0, ax); ay = fmaf(v0.y, c0, ay); az = fmaf(v0.z, c0, az); aw = fmaf(v0.w, c0, aw);
        bx = fmaf(v1.x, c1, bx); by = fmaf(v1.y, c1, by); bz = fmaf(v1.z, c1, bz); bw = fmaf(v1.w, c1, bw);
    }
    if (e < s1) {
        int i0 = pack[e];
        float c0 = dinv[i0] * dn;
        float4 v0 = x4[(size_t)i0 * 16 + l16];
        ax = fmaf(v0.x, c0, ax); ay = fmaf(v0.y, c0, ay); az = fmaf(v0.z, c0, az); aw = fmaf(v0.w, c0, aw);
    }
    float4 out;
    out.x = ax + bx; out.y = ay + by; out.z = az + bz; out.w = aw + bw;
    reinterpret_cast<float4*>(z)[(size_t)n * 16 + l16] = out;
}

// y = z @ W + b (optional relu). 64-row tile/block, no per-thread arrays.
template <int RELU>
__global__ __launch_bounds__(256) void k_gemm(const float* __restrict__ z,
                                              const float* __restrict__ W,
                                              const float* __restrict__ b,
                                              float* __restrict__ y, int N) {
    __shared__ float Wl[D * D];   // Wl[k*64 + col]
    __shared__ float zT[D][68];   // zT[k][row]; pitch 68 keeps rows 16B-aligned
    int t = threadIdx.x;
    int n0 = blockIdx.x * 64;

    #pragma unroll
    for (int r = 0; r < 4; ++r) {
        float4 wv = reinterpret_cast<const float4*>(W)[t + 256 * r];
        *reinterpret_cast<float4*>(&Wl[(t + 256 * r) * 4]) = wv;
    }
    {
        int col4 = (t & 15) * 4;
        int row_base = t >> 4;
        #pragma unroll
        for (int rr = 0; rr < 4; ++rr) {
            int row = row_base + rr * 16;
            int n = n0 + row;
            float4 v = make_float4(0.f, 0.f, 0.f, 0.f);
            if (n < N) v = *reinterpret_cast<const float4*>(&z[(size_t)n * D + col4]);
            zT[col4 + 0][row] = v.x;
            zT[col4 + 1][row] = v.y;
            zT[col4 + 2][row] = v.z;
            zT[col4 + 3][row] = v.w;
        }
    }
    int col4 = (t & 15) * 4;
    int row4 = (t >> 4) * 4;
    __syncthreads();

    float4 a0 = make_float4(0.f, 0.f, 0.f, 0.f);
    float4 a1 = make_float4(0.f, 0.f, 0.f, 0.f);
    float4 a2 = make_float4(0.f, 0.f, 0.f, 0.f);
    float4 a3 = make_float4(0.f, 0.f, 0.f, 0.f);
    #pragma unroll 16
    for (int k = 0; k < D; ++k) {
        float4 zv = *reinterpret_cast<const float4*>(&zT[k][row4]);
        float4 wv = *reinterpret_cast<const float4*>(&Wl[k * D + col4]);
        a0.x = fmaf(zv.x, wv.x, a0.x); a0.y = fmaf(zv.x, wv.y, a0.y);
        a0.z = fmaf(zv.x, wv.z, a0.z); a0.w = fmaf(zv.x, wv.w, a0.w);
        a1.x = fmaf(zv.y, wv.x, a1.x); a1.y = fmaf(zv.y, wv.y, a1.y);
        a1.z = fmaf(zv.y, wv.z, a1.z); a1.w = fmaf(zv.y, wv.w, a1.w);
        a2.x = fmaf(zv.z, wv.x, a2.x); a2.y = fmaf(zv.z, wv.y, a2.y);
        a2.z = fmaf(zv.z, wv.z, a2.z); a2.w = fmaf(zv.z, wv.w, a2.w);
        a3.x = fmaf(zv.w, wv.x, a3.x); a3.y = fmaf(zv.w, wv.y, a3.y);
        a3.z = fmaf(zv.w, wv.z, a3.z); a3.w = fmaf(zv.w, wv.w, a3.w);
    }
    float4 bv = *reinterpret_cast<const float4*>(&b[col4]);
    float4 r0 = make_float4(a0.x + bv.x, a0.y + bv.y, a0.z + bv.z, a0.w + bv.w);
    float4 r1 = make_float4(a1.x + bv.x, a1.y + bv.y, a1.z + bv.z, a1.w + bv.w);
    float4 r2 = make_float4(a2.x + bv.x, a2.y + bv.y, a2.z + bv.z, a2.w + bv.w);
    float4 r3 = make_float4(a3.x + bv.x, a3.y + bv.y, a3.z + bv.z, a3.w + bv.w);
    if (RELU) {
        r0.x = fmaxf(r0.x, 0.f); r0.y = fmaxf(r0.y, 0.f); r0.z = fmaxf(r0.z, 0.f); r0.w = fmaxf(r0.w, 0.f);
        r1.x = fmaxf(r1.x, 0.f); r1.y = fmaxf(r1.y, 0.f); r1.z = fmaxf(r1.z, 0.f); r1.w = fmaxf(r1.w, 0.f);
        r2.x = fmaxf(r2.x, 0.f); r2.y = fmaxf(r2.y, 0.f); r2.z = fmaxf(r2.z, 0.f); r2.w = fmaxf(r2.w, 0.f);
        r3.x = fmaxf(r3.x, 0.f); r3.y = fmaxf(r3.y, 0.f); r3.z = fmaxf(r3.z, 0.f); r3.w = fmaxf(r3.w, 0.f);
    }
    int n = n0 + row4;
    if (n + 0 < N) *reinterpret_cast<float4*>(&y[(size_t)(n + 0) * D + col4]) = r0;
    if (n + 1 < N) *reinterpret_cast<float4*>(&y[(size_t)(n + 1) * D + col4]) = r1;
    if (n + 2 < N) *reinterpret_cast<float4*>(&y[(size_t)(n + 2) * D + col4]) = r2;
    if (n + 3 < N) *reinterpret_cast<float4*>(&y[(size_t)(n + 3) * D + col4]) = r3;
}

// Dual GEMM: reads z once, produces ya = z@Wa+ba and yb = z@Wb+bb.
// In-place safe for yb==z: block stages its own rows in LDS behind the barrier.
__global__ __launch_bounds__(256) void k_gemm_dual(const float* __restrict__ z,
                                                   const float* __restrict__ Wa,
                                                   const float* __restrict__ ba,
                                                   const float* __restrict__ Wb,
                                                   const float* __restrict__ bb,
                                                   float* __restrict__ ya,
                                                   float* __restrict__ yb, int N) {
    __shared__ float Wla[D * D];
    __shared__ float Wlb[D * D];
    __shared__ float zT[D][68];
    int t = threadIdx.x;
    int n0 = blockIdx.x * 64;

    #pragma unroll
    for (int r = 0; r < 4; ++r) {
        float4 wv = reinterpret_cast<const float4*>(Wa)[t + 256 * r];
        *reinterpret_cast<float4*>(&Wla[(t + 256 * r) * 4]) = wv;
        float4 wv2 = reinterpret_cast<const float4*>(Wb)[t + 256 * r];
        *reinterpret_cast<float4*>(&Wlb[(t + 256 * r) * 4]) = wv2;
    }
    {
        int col4 = (t & 15) * 4;
        int row_base = t >> 4;
        #pragma unroll
        for (int rr = 0; rr < 4; ++rr) {
            int row = row_base + rr * 16;
            int n = n0 + row;
            float4 v = make_float4(0.f, 0.f, 0.f, 0.f);
            if (n < N) v = *reinterpret_cast<const float4*>(&z[(size_t)n * D + col4]);
            zT[col4 + 0][row] = v.x;
            zT[col4 + 1][row] = v.y;
            zT[col4 + 2][row] = v.z;
            zT[col4 + 3][row] = v.w;
        }
    }
    int col4 = (t & 15) * 4;
    int row4 = (t >> 4) * 4;
    __syncthreads();

    float4 a0 = make_float4(0.f, 0.f, 0.f, 0.f), a1 = a0, a2 = a0, a3 = a0;
    float4 c0 = a0, c1 = a0, c2 = a0, c3 = a0;
    #pragma unroll 8
    for (int k = 0; k < D; ++k) {
        float4 zv = *reinterpret_cast<const float4*>(&zT[k][row4]);
        float4 wv = *reinterpret_cast<const float4*>(&Wla[k * D + col4]);
        float4 uv = *reinterpret_cast<const float4*>(&Wlb[k * D + col4]);
        a0.x = fmaf(zv.x, wv.x, a0.x); a0.y = fmaf(zv.x, wv.y, a0.y);
        a0.z = fmaf(zv.x, wv.z, a0.z); a0.w = fmaf(zv.x, wv.w, a0.w);
        a1.x = fmaf(zv.y, wv.x, a1.x); a1.y = fmaf(zv.y, wv.y, a1.y);
        a1.z = fmaf(zv.y, wv.z, a1.z); a1.w = fmaf(zv.y, wv.w, a1.w);
        a2.x = fmaf(zv.z, wv.x, a2.x); a2.y = fmaf(zv.z, wv.y, a2.y);
        a2.z = fmaf(zv.z, wv.z, a2.z); a2.w = fmaf(zv.z, wv.w, a2.w);
        a3.x = fmaf(zv.w, wv.x, a3.x); a3.y = fmaf(zv.w, wv.y, a3.y);
        a3.z = fmaf(zv.w, wv.z, a3.z); a3.w = fmaf(zv.w, wv.w, a3.w);
        c0.x = fmaf(zv.x, uv.x, c0.x); c0.y = fmaf(zv.x, uv.y, c0.y);
        c0.z = fmaf(zv.x, uv.z, c0.z); c0.w = fmaf(zv.x, uv.w, c0.w);
        c1.x = fmaf(zv.y, uv.x, c1.x); c1.y = fmaf(zv.y, uv.y, c1.y);
        c1.z = fmaf(zv.y, uv.z, c1.z); c1.w = fmaf(zv.y, uv.w, c1.w);
        c2.x = fmaf(zv.z, uv.x, c2.x); c2.y = fmaf(zv.z, uv.y, c2.y);
        c2.z = fmaf(zv.z, uv.z, c2.z); c2.w = fmaf(zv.z, uv.w, c2.w);
        c3.x = fmaf(zv.w, uv.x, c3.x); c3.y = fmaf(zv.w, uv.y, c3.y);
        c3.z = fmaf(zv.w, uv.z, c3.z); c3.w = fmaf(zv.w, uv.w, c3.w);
    }
    float4 bav = *reinterpret_cast<const float4*>(&ba[col4]);
    float4 bbv = *reinterpret_cast<const float4*>(&bb[col4]);
    int n = n0 + row4;
    if (n + 0 < N) {
        *reinterpret_cast<float4*>(&ya[(size_t)(n + 0) * D + col4]) =
            make_float4(a0.x + bav.x, a0.y + bav.y, a0.z + bav.z, a0.w + bav.w);
        *reinterpret_cast<float4*>(&yb[(size_t)(n + 0) * D + col4]) =
            make_float4(c0.x + bbv.x, c0.y + bbv.y, c0.z + bbv.z, c0.w + bbv.w);
    }
    if (n + 1 < N) {
        *reinterpret_cast<float4*>(&ya[(size_t)(n + 1) * D + col4]) =
            make_float4(a1.x + bav.x, a1.y + bav.y, a1.z + bav.z, a1.w + bav.w);
        *reinterpret_cast<float4*>(&yb[(size_t)(n + 1) * D + col4]) =
            make_float4(c1.x + bbv.x, c1.y + bbv.y, c1.z + bbv.z, c1.w + bbv.w);
    }
    if (n + 2 < N) {
        *reinterpret_cast<float4*>(&ya[(size_t)(n + 2) * D + col4]) =
            make_float4(a2.x + bav.x, a2.y + bav.y, a2.z + bav.z, a2.w + bav.w);
        *reinterpret_cast<float4*>(&yb[(size_t)(n + 2) * D + col4]) =
            make_float4(c2.x + bbv.x, c2.y + bbv.y, c2.z + bbv.z, c2.w + bbv.w);
    }
    if (n + 3 < N) {
        *reinterpret_cast<float4*>(&ya[(size_t)(n + 3) * D + col4]) =
            make_float4(a3.x + bav.x, a3.y + bav.y, a3.z + bav.z, a3.w + bav.w);
        *reinterpret_cast<float4*>(&yb[(size_t)(n + 3) * D + col4]) =
            make_float4(c3.x + bbv.x, c3.y + bbv.y, c3.z + bbv.z, c3.w + bbv.w);
    }
}

extern "C" void kernel_launch(void* const* d_in, const int* in_sizes, int n_in,
                              void* d_out, int out_size, void* d_ws, size_t ws_size,
                              hipStream_t stream) {
    const float* x0  = (const float*)d_in[0];
    const int*   ei  = (const int*)d_in[1];
    const float* W1  = (const float*)d_in[2];
    const float* b1  = (const float*)d_in[3];
    const float* W2  = (const float*)d_in[4];
    const float* b2  = (const float*)d_in[5];
    const float* Wsc = (const float*)d_in[6];
    const float* bs  = (const float*)d_in[7];
    const float* Wmu = (const float*)d_in[8];
    const float* bmu = (const float*)d_in[9];
    const float* Wlv = (const float*)d_in[10];
    const float* blv = (const float*)d_in[11];

    int N = in_sizes[0] / D;
    int E = in_sizes[1] / 2;
    const int* src = ei;
    const int* dst = ei + E;

    char* ws = (char*)d_ws;
    size_t off = 0;
    auto alloc = [&](size_t bytes) {
        char* p = ws + off;
        off += (bytes + 255) & ~(size_t)255;
        return p;
    };
    int*   cnt  = (int*)alloc((size_t)N * 4);
    int*   rp   = (int*)alloc((size_t)(N + 1) * 4);
    float* dinv = (float*)alloc((size_t)N * 4);
    int NB = (N + 255) / 256;  // 196 <= 256: single-block scan2 is valid
    int* part = (int*)alloc((size_t)NB * 4);
    int* boff = (int*)alloc((size_t)NB * 4);
    int* rank = (int*)alloc((size_t)E * 4);
    int* pack = (int*)alloc((size_t)E * 4);

    float* h    = (float*)d_out;                   // scratch; finally holds mu
    float* zbuf = (float*)d_out + (size_t)N * D;   // scratch; finally holds logvar

    int EB = (E + 255) / 256;
    k_zero <<<NB, 256, 0, stream>>>(cnt, N);
    k_deg  <<<EB, 256, 0, stream>>>(dst, cnt, rank, E);
    k_scan1<<<NB, 256, 0, stream>>>(cnt, part, N);
    k_scan2<<<1, 256, 0, stream>>>(part, boff, NB);
    k_scan3<<<NB, 256, 0, stream>>>(cnt, boff, rp, dinv, N, E);
    k_fill <<<EB, 256, 0, stream>>>(src, dst, rank, rp, pack, E);

    int AB = (N + 15) / 16;   // 16 nodes per 256-thread block (4 per wave)
    int GB = (N + 63) / 64;
    // agg(x)@W == agg(x@W) by linearity; mu/logvar share the last aggregation.
    k_agg   <<<AB, 256, 0, stream>>>(x0, rp, pack, dinv, zbuf, N);
    k_gemm<0><<<GB, 256, 0, stream>>>(zbuf, W1, b1, h, N);
    k_agg   <<<AB, 256, 0, stream>>>(h, rp, pack, dinv, zbuf, N);
    k_gemm<0><<<GB, 256, 0, stream>>>(zbuf, W2, b2, h, N);
    k_agg   <<<AB, 256, 0, stream>>>(h, rp, pack, dinv, zbuf, N);
    k_gemm<1><<<GB, 256, 0, stream>>>(zbuf, Wsc, bs, h, N);
    k_agg   <<<AB, 256, 0, stream>>>(h, rp, pack, dinv, zbuf, N);
    // mu -> d_out first half; logvar in-place over zbuf (second half)
    k_gemm_dual<<<GB, 256, 0, stream>>>(zbuf, Wmu, bmu, Wlv, blv, (float*)d_out, zbuf, N);
}

// Round 5
// 242.689 us; speedup vs baseline: 7.7017x; 1.0059x over previous
//
#include <hip/hip_runtime.h>

#define D 64

__global__ void k_zero4(float4* __restrict__ p, int n4) {
    int i = blockIdx.x * 256 + threadIdx.x;
    if (i < n4) p[i] = make_float4(0.f, 0.f, 0.f, 0.f);
}

// rank[e] = this edge's position within its dst node's list (counting-sort rank).
__global__ void k_deg(const int* __restrict__ dst, int* __restrict__ cnt,
                      int* __restrict__ rank, int E) {
    int e = blockIdx.x * 256 + threadIdx.x;
    if (e < E) rank[e] = atomicAdd(&cnt[dst[e]], 1);
}

// NOTE: scans operate on PADDED counts ((v+7)&~7) so every CSR list is a multiple of 8.
__global__ void k_scan1(const int* __restrict__ cnt, int* __restrict__ part, int N) {
    __shared__ int s[256];
    int t = threadIdx.x;
    int i = blockIdx.x * 256 + t;
    int v = (i < N) ? cnt[i] : 0;
    s[t] = (v + 7) & ~7;
    __syncthreads();
    for (int d = 128; d > 0; d >>= 1) {
        if (t < d) s[t] += s[t + d];
        __syncthreads();
    }
    if (t == 0) part[blockIdx.x] = s[0];
}

__global__ void k_scan2(const int* __restrict__ part, int* __restrict__ boff, int nb) {
    __shared__ int s[256];
    int t = threadIdx.x;
    int v = (t < nb) ? part[t] : 0;
    s[t] = v;
    __syncthreads();
    for (int d = 1; d < 256; d <<= 1) {
        int add = (t >= d) ? s[t - d] : 0;
        __syncthreads();
        s[t] += add;
        __syncthreads();
    }
    if (t < nb) boff[t] = s[t] - v;  // exclusive prefix of block partials
}

__global__ void k_scan3(const int* __restrict__ cnt, const int* __restrict__ boff,
                        int* __restrict__ rp, float* __restrict__ dinv, int N) {
    __shared__ int s[256];
    int t = threadIdx.x;
    int i = blockIdx.x * 256 + t;
    int v = (i < N) ? cnt[i] : 0;
    int pv = (v + 7) & ~7;
    s[t] = pv;
    __syncthreads();
    for (int d = 1; d < 256; d <<= 1) {
        int add = (t >= d) ? s[t - d] : 0;
        __syncthreads();
        s[t] += add;
        __syncthreads();
    }
    if (i < N) {
        int excl = boff[blockIdx.x] + s[t] - pv;
        rp[i] = excl;
        dinv[i] = 1.0f / sqrtf((float)v + 1.0f);  // deg includes self-loop (+1)
        if (i == N - 1) rp[N] = excl + pv;
    }
}

// Atomic-free scatter; 8B payload (src, dinv[src]) so k_agg has no dinv gather.
__global__ void k_fill(const int* __restrict__ src, const int* __restrict__ dst,
                       const int* __restrict__ rank, const int* __restrict__ rp,
                       const float* __restrict__ dinv, int2* __restrict__ pack, int E) {
    int e = blockIdx.x * 256 + threadIdx.x;
    if (e < E) {
        int s = src[e];
        int2 p;
        p.x = s;
        p.y = __float_as_int(dinv[s]);
        pack[rp[dst[e]] + rank[e]] = p;
    }
}

// 4 nodes per wave, float4 per lane (16 lanes x 16B = one 256B row per group).
// Lists are padded to x8 (dummy src=0,w=0 => exact no-op): single 8-wide pipelined loop,
// pack batch for iteration i+1 loaded as 4x int4 while iteration i's gathers are in flight.
__global__ void k_agg(const float* __restrict__ x, const int* __restrict__ rp,
                      const int* __restrict__ packi, const float* __restrict__ dinv,
                      float* __restrict__ z, int N) {
    int gt = blockIdx.x * blockDim.x + threadIdx.x;
    int wid = gt >> 6;
    int lane = threadIdx.x & 63;
    int g = lane >> 4;      // node group within wave (0..3)
    int l16 = lane & 15;    // lane within group: owns features 4*l16..4*l16+3
    int n = wid * 4 + g;
    if (n >= N) return;
    int s0 = rp[n], s1 = rp[n + 1];   // both multiples of 8
    float dn = dinv[n];
    const float4* x4 = reinterpret_cast<const float4*>(x);
    const int4* pk = reinterpret_cast<const int4*>(packi);  // int4 = 2 edge records
    float4 sv = x4[(size_t)n * 16 + l16];
    float dnn = dn * dn;
    float ax = sv.x * dnn, ay = sv.y * dnn, az = sv.z * dnn, aw = sv.w * dnn;
    float bx = 0.f, by = 0.f, bz = 0.f, bw = 0.f;

    int e = s0;
    int4 q0, q1, q2, q3;
    if (e < s1) {
        int h = e >> 1;
        q0 = pk[h]; q1 = pk[h + 1]; q2 = pk[h + 2]; q3 = pk[h + 3];
    }
    while (e < s1) {
        // issue 8 row-gathers for the current batch
        float4 v0 = x4[(size_t)q0.x * 16 + l16];
        float4 v1 = x4[(size_t)q0.z * 16 + l16];
        float4 v2 = x4[(size_t)q1.x * 16 + l16];
        float4 v3 = x4[(size_t)q1.z * 16 + l16];
        float4 v4 = x4[(size_t)q2.x * 16 + l16];
        float4 v5 = x4[(size_t)q2.z * 16 + l16];
        float4 v6 = x4[(size_t)q3.x * 16 + l16];
        float4 v7 = x4[(size_t)q3.z * 16 + l16];
        float c0 = __int_as_float(q0.y) * dn, c1 = __int_as_float(q0.w) * dn;
        float c2 = __int_as_float(q1.y) * dn, c3 = __int_as_float(q1.w) * dn;
        float c4 = __int_as_float(q2.y) * dn, c5 = __int_as_float(q2.w) * dn;
        float c6 = __int_as_float(q3.y) * dn, c7 = __int_as_float(q3.w) * dn;
        e += 8;
        if (e < s1) {  // prefetch next batch while gathers are in flight
            int h = e >> 1;
            q0 = pk[h]; q1 = pk[h + 1]; q2 = pk[h + 2]; q3 = pk[h + 3];
        }
        ax = fmaf(v0.x, c0, ax); ay = fmaf(v0.y, c0, ay); az = fmaf(v0.z, c0, az); aw = fmaf(v0.w, c0, aw);
        bx = fmaf(v1.x, c1, bx); by = fmaf(v1.y, c1, by); bz = fmaf(v1.z, c1, bz); bw = fmaf(v1.w, c1, bw);
        ax = fmaf(v2.x, c2, ax); ay = fmaf(v2.y, c2, ay); az = fmaf(v2.z, c2, az); aw = fmaf(v2.w, c2, aw);
        bx = fmaf(v3.x, c3, bx); by = fmaf(v3.y, c3, by); bz = fmaf(v3.z, c3, bz); bw = fmaf(v3.w, c3, bw);
        ax = fmaf(v4.x, c4, ax); ay = fmaf(v4.y, c4, ay); az = fmaf(v4.z, c4, az); aw = fmaf(v4.w, c4, aw);
        bx = fmaf(v5.x, c5, bx); by = fmaf(v5.y, c5, by); bz = fmaf(v5.z, c5, bz); bw = fmaf(v5.w, c5, bw);
        ax = fmaf(v6.x, c6, ax); ay = fmaf(v6.y, c6, ay); az = fmaf(v6.z, c6, az); aw = fmaf(v6.w, c6, aw);
        bx = fmaf(v7.x, c7, bx); by = fmaf(v7.y, c7, by); bz = fmaf(v7.z, c7, bz); bw = fmaf(v7.w, c7, bw);
    }
    float4 out;
    out.x = ax + bx; out.y = ay + by; out.z = az + bz; out.w = aw + bw;
    reinterpret_cast<float4*>(z)[(size_t)n * 16 + l16] = out;
}

// y = z @ W + b (optional relu). 64-row tile/block, no per-thread arrays.
template <int RELU>
__global__ __launch_bounds__(256) void k_gemm(const float* __restrict__ z,
                                              const float* __restrict__ W,
                                              const float* __restrict__ b,
                                              float* __restrict__ y, int N) {
    __shared__ float Wl[D * D];   // Wl[k*64 + col]
    __shared__ float zT[D][68];   // zT[k][row]; pitch 68 keeps rows 16B-aligned
    int t = threadIdx.x;
    int n0 = blockIdx.x * 64;

    #pragma unroll
    for (int r = 0; r < 4; ++r) {
        float4 wv = reinterpret_cast<const float4*>(W)[t + 256 * r];
        *reinterpret_cast<float4*>(&Wl[(t + 256 * r) * 4]) = wv;
    }
    {
        int col4 = (t & 15) * 4;
        int row_base = t >> 4;
        #pragma unroll
        for (int rr = 0; rr < 4; ++rr) {
            int row = row_base + rr * 16;
            int n = n0 + row;
            float4 v = make_float4(0.f, 0.f, 0.f, 0.f);
            if (n < N) v = *reinterpret_cast<const float4*>(&z[(size_t)n * D + col4]);
            zT[col4 + 0][row] = v.x;
            zT[col4 + 1][row] = v.y;
            zT[col4 + 2][row] = v.z;
            zT[col4 + 3][row] = v.w;
        }
    }
    int col4 = (t & 15) * 4;
    int row4 = (t >> 4) * 4;
    __syncthreads();

    float4 a0 = make_float4(0.f, 0.f, 0.f, 0.f);
    float4 a1 = make_float4(0.f, 0.f, 0.f, 0.f);
    float4 a2 = make_float4(0.f, 0.f, 0.f, 0.f);
    float4 a3 = make_float4(0.f, 0.f, 0.f, 0.f);
    #pragma unroll 16
    for (int k = 0; k < D; ++k) {
        float4 zv = *reinterpret_cast<const float4*>(&zT[k][row4]);
        float4 wv = *reinterpret_cast<const float4*>(&Wl[k * D + col4]);
        a0.x = fmaf(zv.x, wv.x, a0.x); a0.y = fmaf(zv.x, wv.y, a0.y);
        a0.z = fmaf(zv.x, wv.z, a0.z); a0.w = fmaf(zv.x, wv.w, a0.w);
        a1.x = fmaf(zv.y, wv.x, a1.x); a1.y = fmaf(zv.y, wv.y, a1.y);
        a1.z = fmaf(zv.y, wv.z, a1.z); a1.w = fmaf(zv.y, wv.w, a1.w);
        a2.x = fmaf(zv.z, wv.x, a2.x); a2.y = fmaf(zv.z, wv.y, a2.y);
        a2.z = fmaf(zv.z, wv.z, a2.z); a2.w = fmaf(zv.z, wv.w, a2.w);
        a3.x = fmaf(zv.w, wv.x, a3.x); a3.y = fmaf(zv.w, wv.y, a3.y);
        a3.z = fmaf(zv.w, wv.z, a3.z); a3.w = fmaf(zv.w, wv.w, a3.w);
    }
    float4 bv = *reinterpret_cast<const float4*>(&b[col4]);
    float4 r0 = make_float4(a0.x + bv.x, a0.y + bv.y, a0.z + bv.z, a0.w + bv.w);
    float4 r1 = make_float4(a1.x + bv.x, a1.y + bv.y, a1.z + bv.z, a1.w + bv.w);
    float4 r2 = make_float4(a2.x + bv.x, a2.y + bv.y, a2.z + bv.z, a2.w + bv.w);
    float4 r3 = make_float4(a3.x + bv.x, a3.y + bv.y, a3.z + bv.z, a3.w + bv.w);
    if (RELU) {
        r0.x = fmaxf(r0.x, 0.f); r0.y = fmaxf(r0.y, 0.f); r0.z = fmaxf(r0.z, 0.f); r0.w = fmaxf(r0.w, 0.f);
        r1.x = fmaxf(r1.x, 0.f); r1.y = fmaxf(r1.y, 0.f); r1.z = fmaxf(r1.z, 0.f); r1.w = fmaxf(r1.w, 0.f);
        r2.x = fmaxf(r2.x, 0.f); r2.y = fmaxf(r2.y, 0.f); r2.z = fmaxf(r2.z, 0.f); r2.w = fmaxf(r2.w, 0.f);
        r3.x = fmaxf(r3.x, 0.f); r3.y = fmaxf(r3.y, 0.f); r3.z = fmaxf(r3.z, 0.f); r3.w = fmaxf(r3.w, 0.f);
    }
    int n = n0 + row4;
    if (n + 0 < N) *reinterpret_cast<float4*>(&y[(size_t)(n + 0) * D + col4]) = r0;
    if (n + 1 < N) *reinterpret_cast<float4*>(&y[(size_t)(n + 1) * D + col4]) = r1;
    if (n + 2 < N) *reinterpret_cast<float4*>(&y[(size_t)(n + 2) * D + col4]) = r2;
    if (n + 3 < N) *reinterpret_cast<float4*>(&y[(size_t)(n + 3) * D + col4]) = r3;
}

// Dual GEMM: reads z once, produces ya = z@Wa+ba and yb = z@Wb+bb.
// In-place safe for yb==z: block stages its own rows in LDS behind the barrier.
__global__ __launch_bounds__(256) void k_gemm_dual(const float* __restrict__ z,
                                                   const float* __restrict__ Wa,
                                                   const float* __restrict__ ba,
                                                   const float* __restrict__ Wb,
                                                   const float* __restrict__ bb,
                                                   float* __restrict__ ya,
                                                   float* __restrict__ yb, int N) {
    __shared__ float Wla[D * D];
    __shared__ float Wlb[D * D];
    __shared__ float zT[D][68];
    int t = threadIdx.x;
    int n0 = blockIdx.x * 64;

    #pragma unroll
    for (int r = 0; r < 4; ++r) {
        float4 wv = reinterpret_cast<const float4*>(Wa)[t + 256 * r];
        *reinterpret_cast<float4*>(&Wla[(t + 256 * r) * 4]) = wv;
        float4 wv2 = reinterpret_cast<const float4*>(Wb)[t + 256 * r];
        *reinterpret_cast<float4*>(&Wlb[(t + 256 * r) * 4]) = wv2;
    }
    {
        int col4 = (t & 15) * 4;
        int row_base = t >> 4;
        #pragma unroll
        for (int rr = 0; rr < 4; ++rr) {
            int row = row_base + rr * 16;
            int n = n0 + row;
            float4 v = make_float4(0.f, 0.f, 0.f, 0.f);
            if (n < N) v = *reinterpret_cast<const float4*>(&z[(size_t)n * D + col4]);
            zT[col4 + 0][row] = v.x;
            zT[col4 + 1][row] = v.y;
            zT[col4 + 2][row] = v.z;
            zT[col4 + 3][row] = v.w;
        }
    }
    int col4 = (t & 15) * 4;
    int row4 = (t >> 4) * 4;
    __syncthreads();

    float4 a0 = make_float4(0.f, 0.f, 0.f, 0.f), a1 = a0, a2 = a0, a3 = a0;
    float4 c0 = a0, c1 = a0, c2 = a0, c3 = a0;
    #pragma unroll 8
    for (int k = 0; k < D; ++k) {
        float4 zv = *reinterpret_cast<const float4*>(&zT[k][row4]);
        float4 wv = *reinterpret_cast<const float4*>(&Wla[k * D + col4]);
        float4 uv = *reinterpret_cast<const float4*>(&Wlb[k * D + col4]);
        a0.x = fmaf(zv.x, wv.x, a0.x); a0.y = fmaf(zv.x, wv.y, a0.y);
        a0.z = fmaf(zv.x, wv.z, a0.z); a0.w = fmaf(zv.x, wv.w, a0.w);
        a1.x = fmaf(zv.y, wv.x, a1.x); a1.y = fmaf(zv.y, wv.y, a1.y);
        a1.z = fmaf(zv.y, wv.z, a1.z); a1.w = fmaf(zv.y, wv.w, a1.w);
        a2.x = fmaf(zv.z, wv.x, a2.x); a2.y = fmaf(zv.z, wv.y, a2.y);
        a2.z = fmaf(zv.z, wv.z, a2.z); a2.w = fmaf(zv.z, wv.w, a2.w);
        a3.x = fmaf(zv.w, wv.x, a3.x); a3.y = fmaf(zv.w, wv.y, a3.y);
        a3.z = fmaf(zv.w, wv.z, a3.z); a3.w = fmaf(zv.w, wv.w, a3.w);
        c0.x = fmaf(zv.x, uv.x, c0.x); c0.y = fmaf(zv.x, uv.y, c0.y);
        c0.z = fmaf(zv.x, uv.z, c0.z); c0.w = fmaf(zv.x, uv.w, c0.w);
        c1.x = fmaf(zv.y, uv.x, c1.x); c1.y = fmaf(zv.y, uv.y, c1.y);
        c1.z = fmaf(zv.y, uv.z, c1.z); c1.w = fmaf(zv.y, uv.w, c1.w);
        c2.x = fmaf(zv.z, uv.x, c2.x); c2.y = fmaf(zv.z, uv.y, c2.y);
        c2.z = fmaf(zv.z, uv.z, c2.z); c2.w = fmaf(zv.z, uv.w, c2.w);
        c3.x = fmaf(zv.w, uv.x, c3.x); c3.y = fmaf(zv.w, uv.y, c3.y);
        c3.z = fmaf(zv.w, uv.z, c3.z); c3.w = fmaf(zv.w, uv.w, c3.w);
    }
    float4 bav = *reinterpret_cast<const float4*>(&ba[col4]);
    float4 bbv = *reinterpret_cast<const float4*>(&bb[col4]);
    int n = n0 + row4;
    if (n + 0 < N) {
        *reinterpret_cast<float4*>(&ya[(size_t)(n + 0) * D + col4]) =
            make_float4(a0.x + bav.x, a0.y + bav.y, a0.z + bav.z, a0.w + bav.w);
        *reinterpret_cast<float4*>(&yb[(size_t)(n + 0) * D + col4]) =
            make_float4(c0.x + bbv.x, c0.y + bbv.y, c0.z + bbv.z, c0.w + bbv.w);
    }
    if (n + 1 < N) {
        *reinterpret_cast<float4*>(&ya[(size_t)(n + 1) * D + col4]) =
            make_float4(a1.x + bav.x, a1.y + bav.y, a1.z + bav.z, a1.w + bav.w);
        *reinterpret_cast<float4*>(&yb[(size_t)(n + 1) * D + col4]) =
            make_float4(c1.x + bbv.x, c1.y + bbv.y, c1.z + bbv.z, c1.w + bbv.w);
    }
    if (n + 2 < N) {
        *reinterpret_cast<float4*>(&ya[(size_t)(n + 2) * D + col4]) =
            make_float4(a2.x + bav.x, a2.y + bav.y, a2.z + bav.z, a2.w + bav.w);
        *reinterpret_cast<float4*>(&yb[(size_t)(n + 2) * D + col4]) =
            make_float4(c2.x + bbv.x, c2.y + bbv.y, c2.z + bbv.z, c2.w + bbv.w);
    }
    if (n + 3 < N) {
        *reinterpret_cast<float4*>(&ya[(size_t)(n + 3) * D + col4]) =
            make_float4(a3.x + bav.x, a3.y + bav.y, a3.z + bav.z, a3.w + bav.w);
        *reinterpret_cast<float4*>(&yb[(size_t)(n + 3) * D + col4]) =
            make_float4(c3.x + bbv.x, c3.y + bbv.y, c3.z + bbv.z, c3.w + bbv.w);
    }
}

extern "C" void kernel_launch(void* const* d_in, const int* in_sizes, int n_in,
                              void* d_out, int out_size, void* d_ws, size_t ws_size,
                              hipStream_t stream) {
    const float* x0  = (const float*)d_in[0];
    const int*   ei  = (const int*)d_in[1];
    const float* W1  = (const float*)d_in[2];
    const float* b1  = (const float*)d_in[3];
    const float* W2  = (const float*)d_in[4];
    const float* b2  = (const float*)d_in[5];
    const float* Wsc = (const float*)d_in[6];
    const float* bs  = (const float*)d_in[7];
    const float* Wmu = (const float*)d_in[8];
    const float* bmu = (const float*)d_in[9];
    const float* Wlv = (const float*)d_in[10];
    const float* blv = (const float*)d_in[11];

    int N = in_sizes[0] / D;
    int E = in_sizes[1] / 2;
    const int* src = ei;
    const int* dst = ei + E;

    char* ws = (char*)d_ws;
    size_t off = 0;
    auto alloc = [&](size_t bytes) {
        char* p = ws + off;
        off += (bytes + 255) & ~(size_t)255;
        return p;
    };
    int*   rp   = (int*)alloc((size_t)(N + 1) * 4);
    float* dinv = (float*)alloc((size_t)N * 4);
    int NB = (N + 255) / 256;  // 196 <= 256: single-block scan2 is valid
    int* part = (int*)alloc((size_t)NB * 4);
    int* boff = (int*)alloc((size_t)NB * 4);
    int* rank = (int*)alloc((size_t)E * 4);
    // cnt and pack adjacent -> one contiguous zero-fill covers both
    char* zero_base = ws + off;
    int*  cnt  = (int*)alloc((size_t)N * 4);
    int2* pack = (int2*)alloc(((size_t)E + 8 * (size_t)N) * 8);  // padded CSR (x8 lists)
    size_t zero_bytes = (size_t)((char*)(pack + E + 8 * (size_t)N) - zero_base);
    int n4 = (int)((zero_bytes + 15) / 16);

    float* h    = (float*)d_out;                   // scratch; finally holds mu
    float* zbuf = (float*)d_out + (size_t)N * D;   // scratch; finally holds logvar

    int EB = (E + 255) / 256;
    k_zero4<<<(n4 + 255) / 256, 256, 0, stream>>>((float4*)zero_base, n4);
    k_deg  <<<EB, 256, 0, stream>>>(dst, cnt, rank, E);
    k_scan1<<<NB, 256, 0, stream>>>(cnt, part, N);
    k_scan2<<<1, 256, 0, stream>>>(part, boff, NB);
    k_scan3<<<NB, 256, 0, stream>>>(cnt, boff, rp, dinv, N);
    k_fill <<<EB, 256, 0, stream>>>(src, dst, rank, rp, dinv, pack, E);

    int AB = (N + 15) / 16;   // 16 nodes per 256-thread block (4 per wave)
    int GB = (N + 63) / 64;
    // agg(x)@W == agg(x@W) by linearity; mu/logvar share the last aggregation.
    k_agg   <<<AB, 256, 0, stream>>>(x0, rp, (const int*)pack, dinv, zbuf, N);
    k_gemm<0><<<GB, 256, 0, stream>>>(zbuf, W1, b1, h, N);
    k_agg   <<<AB, 256, 0, stream>>>(h, rp, (const int*)pack, dinv, zbuf, N);
    k_gemm<0><<<GB, 256, 0, stream>>>(zbuf, W2, b2, h, N);
    k_agg   <<<AB, 256, 0, stream>>>(h, rp, (const int*)pack, dinv, zbuf, N);
    k_gemm<1><<<GB, 256, 0, stream>>>(zbuf, Wsc, bs, h, N);
    k_agg   <<<AB, 256, 0, stream>>>(h, rp, (const int*)pack, dinv, zbuf, N);
    // mu -> d_out first half; logvar in-place over zbuf (second half)
    k_gemm_dual<<<GB, 256, 0, stream>>>(zbuf, Wmu, bmu, Wlv, blv, (float*)d_out, zbuf, N);
}

// Round 6
// 189.367 us; speedup vs baseline: 9.8704x; 1.2816x over previous
//
#include <hip/hip_runtime.h>

#define D 64

__global__ void k_zero4(float4* __restrict__ p, int n4) {
    int i = blockIdx.x * 256 + threadIdx.x;
    if (i < n4) p[i] = make_float4(0.f, 0.f, 0.f, 0.f);
}

// 8-way split counters: copy c = (e>>8)&7 (= blockIdx&7). Cuts the same-address
// atomic-return dependency chain (the k_deg latency driver) by 8x.
__global__ void k_deg(const int* __restrict__ dst, int* __restrict__ cnt8,
                      int* __restrict__ rank, int N, int E) {
    int e = blockIdx.x * 256 + threadIdx.x;
    if (e < E) rank[e] = atomicAdd(&cnt8[(size_t)(blockIdx.x & 7) * N + dst[e]], 1);
}

// Scans operate on PADDED totals ((sum+7)&~7) so every CSR list is a multiple of 8.
__global__ void k_scan1(const int* __restrict__ cnt8, int* __restrict__ part, int N) {
    __shared__ int s[256];
    int t = threadIdx.x;
    int i = blockIdx.x * 256 + t;
    int v = 0;
    if (i < N) {
        #pragma unroll
        for (int c = 0; c < 8; ++c) v += cnt8[(size_t)c * N + i];
    }
    s[t] = (v + 7) & ~7;
    __syncthreads();
    for (int d = 128; d > 0; d >>= 1) {
        if (t < d) s[t] += s[t + d];
        __syncthreads();
    }
    if (t == 0) part[blockIdx.x] = s[0];
}

__global__ void k_scan2(const int* __restrict__ part, int* __restrict__ boff, int nb) {
    __shared__ int s[256];
    int t = threadIdx.x;
    int v = (t < nb) ? part[t] : 0;
    s[t] = v;
    __syncthreads();
    for (int d = 1; d < 256; d <<= 1) {
        int add = (t >= d) ? s[t - d] : 0;
        __syncthreads();
        s[t] += add;
        __syncthreads();
    }
    if (t < nb) boff[t] = s[t] - v;  // exclusive prefix of block partials
}

__global__ void k_scan3(const int* __restrict__ cnt8, const int* __restrict__ boff,
                        int* __restrict__ rp, int* __restrict__ off8,
                        float* __restrict__ dinv, int N) {
    __shared__ int s[256];
    int t = threadIdx.x;
    int i = blockIdx.x * 256 + t;
    int vc[8];
    int v = 0;
    if (i < N) {
        #pragma unroll
        for (int c = 0; c < 8; ++c) { vc[c] = cnt8[(size_t)c * N + i]; v += vc[c]; }
    }
    int pv = (v + 7) & ~7;
    s[t] = pv;
    __syncthreads();
    for (int d = 1; d < 256; d <<= 1) {
        int add = (t >= d) ? s[t - d] : 0;
        __syncthreads();
        s[t] += add;
        __syncthreads();
    }
    if (i < N) {
        int excl = boff[blockIdx.x] + s[t] - pv;
        rp[i] = excl;
        dinv[i] = 1.0f / sqrtf((float)v + 1.0f);  // deg includes self-loop (+1)
        int run = excl;
        #pragma unroll
        for (int c = 0; c < 8; ++c) { off8[(size_t)c * N + i] = run; run += vc[c]; }
        if (i == N - 1) rp[N] = excl + pv;
    }
}

// Atomic-free scatter; 8B payload (src, dinv[src]) so k_fused has no dinv gather.
__global__ void k_fill(const int* __restrict__ src, const int* __restrict__ dst,
                       const int* __restrict__ rank, const int* __restrict__ off8,
                       const float* __restrict__ dinv, int2* __restrict__ pack,
                       int N, int E) {
    int e = blockIdx.x * 256 + threadIdx.x;
    if (e < E) {
        int s = src[e];
        int2 p;
        p.x = s;
        p.y = __float_as_int(dinv[s]);
        pack[off8[(size_t)(blockIdx.x & 7) * N + dst[e]] + rank[e]] = p;
    }
}

// Fused aggregate + GEMM (+optional relu). Block = 256 threads = 16 nodes (4/wave).
// Phase 1 (agg): 4 nodes/wave, float4/lane; lists padded to x8 (dummy src=0,w=0 -> no-op);
//   pack batch for iter i+1 prefetched while iter i's 8 row-gathers are in flight.
// Phase 2 (gemm): z-tile (16x68 LDS, padded -> conflict-free) x W (LDS) applied in-block.
// Kills the z HBM round-trip and the separate GEMM dispatch.
template <int RELU>
__global__ __launch_bounds__(256) void k_fused(const float* __restrict__ x,
                                               const int* __restrict__ rp,
                                               const int* __restrict__ packi,
                                               const float* __restrict__ dinv,
                                               const float* __restrict__ W,
                                               const float* __restrict__ b,
                                               float* __restrict__ y, int N) {
    __shared__ float Wl[D * D];     // Wl[k*64+j] = W[k][j]
    __shared__ float zs[16][68];    // padded: rows 272B apart -> gemm reads conflict-free
    int t = threadIdx.x;

    // stage W (completes while agg runs; consumed after the barrier)
    #pragma unroll
    for (int r = 0; r < 4; ++r) {
        float4 wv = reinterpret_cast<const float4*>(W)[t + 256 * r];
        *reinterpret_cast<float4*>(&Wl[(t + 256 * r) * 4]) = wv;
    }

    int lane = t & 63;
    int g = lane >> 4;       // node group within wave
    int l16 = lane & 15;     // owns features 4*l16..4*l16+3
    int r_loc = (t >> 6) * 4 + g;      // local row 0..15
    int n = blockIdx.x * 16 + r_loc;
    if (n < N) {
        int s0 = rp[n], s1 = rp[n + 1];   // multiples of 8
        float dn = dinv[n];
        const float4* x4 = reinterpret_cast<const float4*>(x);
        const int4* pk = reinterpret_cast<const int4*>(packi);
        float4 sv = x4[(size_t)n * 16 + l16];
        float dnn = dn * dn;
        float ax = sv.x * dnn, ay = sv.y * dnn, az = sv.z * dnn, aw = sv.w * dnn;
        float bx = 0.f, by = 0.f, bz = 0.f, bw = 0.f;
        int e = s0;
        int4 q0, q1, q2, q3;
        if (e < s1) {
            int h = e >> 1;
            q0 = pk[h]; q1 = pk[h + 1]; q2 = pk[h + 2]; q3 = pk[h + 3];
        }
        while (e < s1) {
            float4 v0 = x4[(size_t)q0.x * 16 + l16];
            float4 v1 = x4[(size_t)q0.z * 16 + l16];
            float4 v2 = x4[(size_t)q1.x * 16 + l16];
            float4 v3 = x4[(size_t)q1.z * 16 + l16];
            float4 v4 = x4[(size_t)q2.x * 16 + l16];
            float4 v5 = x4[(size_t)q2.z * 16 + l16];
            float4 v6 = x4[(size_t)q3.x * 16 + l16];
            float4 v7 = x4[(size_t)q3.z * 16 + l16];
            float c0 = __int_as_float(q0.y) * dn, c1 = __int_as_float(q0.w) * dn;
            float c2 = __int_as_float(q1.y) * dn, c3 = __int_as_float(q1.w) * dn;
            float c4 = __int_as_float(q2.y) * dn, c5 = __int_as_float(q2.w) * dn;
            float c6 = __int_as_float(q3.y) * dn, c7 = __int_as_float(q3.w) * dn;
            e += 8;
            if (e < s1) {  // prefetch next batch while gathers are in flight
                int h = e >> 1;
                q0 = pk[h]; q1 = pk[h + 1]; q2 = pk[h + 2]; q3 = pk[h + 3];
            }
            ax = fmaf(v0.x, c0, ax); ay = fmaf(v0.y, c0, ay); az = fmaf(v0.z, c0, az); aw = fmaf(v0.w, c0, aw);
            bx = fmaf(v1.x, c1, bx); by = fmaf(v1.y, c1, by); bz = fmaf(v1.z, c1, bz); bw = fmaf(v1.w, c1, bw);
            ax = fmaf(v2.x, c2, ax); ay = fmaf(v2.y, c2, ay); az = fmaf(v2.z, c2, az); aw = fmaf(v2.w, c2, aw);
            bx = fmaf(v3.x, c3, bx); by = fmaf(v3.y, c3, by); bz = fmaf(v3.z, c3, bz); bw = fmaf(v3.w, c3, bw);
            ax = fmaf(v4.x, c4, ax); ay = fmaf(v4.y, c4, ay); az = fmaf(v4.z, c4, az); aw = fmaf(v4.w, c4, aw);
            bx = fmaf(v5.x, c5, bx); by = fmaf(v5.y, c5, by); bz = fmaf(v5.z, c5, bz); bw = fmaf(v5.w, c5, bw);
            ax = fmaf(v6.x, c6, ax); ay = fmaf(v6.y, c6, ay); az = fmaf(v6.z, c6, az); aw = fmaf(v6.w, c6, aw);
            bx = fmaf(v7.x, c7, bx); by = fmaf(v7.y, c7, by); bz = fmaf(v7.z, c7, bz); bw = fmaf(v7.w, c7, bw);
        }
        *reinterpret_cast<float4*>(&zs[r_loc][l16 * 4]) =
            make_float4(ax + bx, ay + by, az + bz, aw + bw);
    }
    __syncthreads();

    // gemm: thread t -> row (t>>4), cols (t&15)*4..+3
    int col4 = (t & 15) * 4;
    int row = t >> 4;
    int nn = blockIdx.x * 16 + row;
    if (nn < N) {
        float4 acc = make_float4(0.f, 0.f, 0.f, 0.f);
        #pragma unroll
        for (int k = 0; k < D; k += 4) {
            float4 zv = *reinterpret_cast<const float4*>(&zs[row][k]);
            float4 w0 = *reinterpret_cast<const float4*>(&Wl[(k + 0) * D + col4]);
            float4 w1 = *reinterpret_cast<const float4*>(&Wl[(k + 1) * D + col4]);
            float4 w2 = *reinterpret_cast<const float4*>(&Wl[(k + 2) * D + col4]);
            float4 w3 = *reinterpret_cast<const float4*>(&Wl[(k + 3) * D + col4]);
            acc.x = fmaf(zv.x, w0.x, acc.x); acc.y = fmaf(zv.x, w0.y, acc.y);
            acc.z = fmaf(zv.x, w0.z, acc.z); acc.w = fmaf(zv.x, w0.w, acc.w);
            acc.x = fmaf(zv.y, w1.x, acc.x); acc.y = fmaf(zv.y, w1.y, acc.y);
            acc.z = fmaf(zv.y, w1.z, acc.z); acc.w = fmaf(zv.y, w1.w, acc.w);
            acc.x = fmaf(zv.z, w2.x, acc.x); acc.y = fmaf(zv.z, w2.y, acc.y);
            acc.z = fmaf(zv.z, w2.z, acc.z); acc.w = fmaf(zv.z, w2.w, acc.w);
            acc.x = fmaf(zv.w, w3.x, acc.x); acc.y = fmaf(zv.w, w3.y, acc.y);
            acc.z = fmaf(zv.w, w3.z, acc.z); acc.w = fmaf(zv.w, w3.w, acc.w);
        }
        float4 bv = *reinterpret_cast<const float4*>(&b[col4]);
        float4 r = make_float4(acc.x + bv.x, acc.y + bv.y, acc.z + bv.z, acc.w + bv.w);
        if (RELU) {
            r.x = fmaxf(r.x, 0.f); r.y = fmaxf(r.y, 0.f);
            r.z = fmaxf(r.z, 0.f); r.w = fmaxf(r.w, 0.f);
        }
        *reinterpret_cast<float4*>(&y[(size_t)nn * D + col4]) = r;
    }
}

// Dual-output variant for the final layer (mu, logvar share the aggregation).
__global__ __launch_bounds__(256) void k_fused_dual(const float* __restrict__ x,
                                                    const int* __restrict__ rp,
                                                    const int* __restrict__ packi,
                                                    const float* __restrict__ dinv,
                                                    const float* __restrict__ Wa,
                                                    const float* __restrict__ ba,
                                                    const float* __restrict__ Wb,
                                                    const float* __restrict__ bb,
                                                    float* __restrict__ ya,
                                                    float* __restrict__ yb, int N) {
    __shared__ float Wla[D * D];
    __shared__ float Wlb[D * D];
    __shared__ float zs[16][68];
    int t = threadIdx.x;

    #pragma unroll
    for (int r = 0; r < 4; ++r) {
        float4 wv = reinterpret_cast<const float4*>(Wa)[t + 256 * r];
        *reinterpret_cast<float4*>(&Wla[(t + 256 * r) * 4]) = wv;
        float4 wv2 = reinterpret_cast<const float4*>(Wb)[t + 256 * r];
        *reinterpret_cast<float4*>(&Wlb[(t + 256 * r) * 4]) = wv2;
    }

    int lane = t & 63;
    int g = lane >> 4;
    int l16 = lane & 15;
    int r_loc = (t >> 6) * 4 + g;
    int n = blockIdx.x * 16 + r_loc;
    if (n < N) {
        int s0 = rp[n], s1 = rp[n + 1];
        float dn = dinv[n];
        const float4* x4 = reinterpret_cast<const float4*>(x);
        const int4* pk = reinterpret_cast<const int4*>(packi);
        float4 sv = x4[(size_t)n * 16 + l16];
        float dnn = dn * dn;
        float ax = sv.x * dnn, ay = sv.y * dnn, az = sv.z * dnn, aw = sv.w * dnn;
        float bx = 0.f, by = 0.f, bz = 0.f, bw = 0.f;
        int e = s0;
        int4 q0, q1, q2, q3;
        if (e < s1) {
            int h = e >> 1;
            q0 = pk[h]; q1 = pk[h + 1]; q2 = pk[h + 2]; q3 = pk[h + 3];
        }
        while (e < s1) {
            float4 v0 = x4[(size_t)q0.x * 16 + l16];
            float4 v1 = x4[(size_t)q0.z * 16 + l16];
            float4 v2 = x4[(size_t)q1.x * 16 + l16];
            float4 v3 = x4[(size_t)q1.z * 16 + l16];
            float4 v4 = x4[(size_t)q2.x * 16 + l16];
            float4 v5 = x4[(size_t)q2.z * 16 + l16];
            float4 v6 = x4[(size_t)q3.x * 16 + l16];
            float4 v7 = x4[(size_t)q3.z * 16 + l16];
            float c0 = __int_as_float(q0.y) * dn, c1 = __int_as_float(q0.w) * dn;
            float c2 = __int_as_float(q1.y) * dn, c3 = __int_as_float(q1.w) * dn;
            float c4 = __int_as_float(q2.y) * dn, c5 = __int_as_float(q2.w) * dn;
            float c6 = __int_as_float(q3.y) * dn, c7 = __int_as_float(q3.w) * dn;
            e += 8;
            if (e < s1) {
                int h = e >> 1;
                q0 = pk[h]; q1 = pk[h + 1]; q2 = pk[h + 2]; q3 = pk[h + 3];
            }
            ax = fmaf(v0.x, c0, ax); ay = fmaf(v0.y, c0, ay); az = fmaf(v0.z, c0, az); aw = fmaf(v0.w, c0, aw);
            bx = fmaf(v1.x, c1, bx); by = fmaf(v1.y, c1, by); bz = fmaf(v1.z, c1, bz); bw = fmaf(v1.w, c1, bw);
            ax = fmaf(v2.x, c2, ax); ay = fmaf(v2.y, c2, ay); az = fmaf(v2.z, c2, az); aw = fmaf(v2.w, c2, aw);
            bx = fmaf(v3.x, c3, bx); by = fmaf(v3.y, c3, by); bz = fmaf(v3.z, c3, bz); bw = fmaf(v3.w, c3, bw);
            ax = fmaf(v4.x, c4, ax); ay = fmaf(v4.y, c4, ay); az = fmaf(v4.z, c4, az); aw = fmaf(v4.w, c4, aw);
            bx = fmaf(v5.x, c5, bx); by = fmaf(v5.y, c5, by); bz = fmaf(v5.z, c5, bz); bw = fmaf(v5.w, c5, bw);
            ax = fmaf(v6.x, c6, ax); ay = fmaf(v6.y, c6, ay); az = fmaf(v6.z, c6, az); aw = fmaf(v6.w, c6, aw);
            bx = fmaf(v7.x, c7, bx); by = fmaf(v7.y, c7, by); bz = fmaf(v7.z, c7, bz); bw = fmaf(v7.w, c7, bw);
        }
        *reinterpret_cast<float4*>(&zs[r_loc][l16 * 4]) =
            make_float4(ax + bx, ay + by, az + bz, aw + bw);
    }
    __syncthreads();

    int col4 = (t & 15) * 4;
    int row = t >> 4;
    int nn = blockIdx.x * 16 + row;
    if (nn < N) {
        float4 acc = make_float4(0.f, 0.f, 0.f, 0.f);
        float4 acd = make_float4(0.f, 0.f, 0.f, 0.f);
        #pragma unroll
        for (int k = 0; k < D; k += 2) {
            float z0 = zs[row][k], z1 = zs[row][k + 1];
            float4 w0 = *reinterpret_cast<const float4*>(&Wla[(k + 0) * D + col4]);
            float4 w1 = *reinterpret_cast<const float4*>(&Wla[(k + 1) * D + col4]);
            float4 u0 = *reinterpret_cast<const float4*>(&Wlb[(k + 0) * D + col4]);
            float4 u1 = *reinterpret_cast<const float4*>(&Wlb[(k + 1) * D + col4]);
            acc.x = fmaf(z0, w0.x, acc.x); acc.y = fmaf(z0, w0.y, acc.y);
            acc.z = fmaf(z0, w0.z, acc.z); acc.w = fmaf(z0, w0.w, acc.w);
            acc.x = fmaf(z1, w1.x, acc.x); acc.y = fmaf(z1, w1.y, acc.y);
            acc.z = fmaf(z1, w1.z, acc.z); acc.w = fmaf(z1, w1.w, acc.w);
            acd.x = fmaf(z0, u0.x, acd.x); acd.y = fmaf(z0, u0.y, acd.y);
            acd.z = fmaf(z0, u0.z, acd.z); acd.w = fmaf(z0, u0.w, acd.w);
            acd.x = fmaf(z1, u1.x, acd.x); acd.y = fmaf(z1, u1.y, acd.y);
            acd.z = fmaf(z1, u1.z, acd.z); acd.w = fmaf(z1, u1.w, acd.w);
        }
        float4 bav = *reinterpret_cast<const float4*>(&ba[col4]);
        float4 bbv = *reinterpret_cast<const float4*>(&bb[col4]);
        *reinterpret_cast<float4*>(&ya[(size_t)nn * D + col4]) =
            make_float4(acc.x + bav.x, acc.y + bav.y, acc.z + bav.z, acc.w + bav.w);
        *reinterpret_cast<float4*>(&yb[(size_t)nn * D + col4]) =
            make_float4(acd.x + bbv.x, acd.y + bbv.y, acd.z + bbv.z, acd.w + bbv.w);
    }
}

extern "C" void kernel_launch(void* const* d_in, const int* in_sizes, int n_in,
                              void* d_out, int out_size, void* d_ws, size_t ws_size,
                              hipStream_t stream) {
    const float* x0  = (const float*)d_in[0];
    const int*   ei  = (const int*)d_in[1];
    const float* W1  = (const float*)d_in[2];
    const float* b1  = (const float*)d_in[3];
    const float* W2  = (const float*)d_in[4];
    const float* b2  = (const float*)d_in[5];
    const float* Wsc = (const float*)d_in[6];
    const float* bs  = (const float*)d_in[7];
    const float* Wmu = (const float*)d_in[8];
    const float* bmu = (const float*)d_in[9];
    const float* Wlv = (const float*)d_in[10];
    const float* blv = (const float*)d_in[11];

    int N = in_sizes[0] / D;
    int E = in_sizes[1] / 2;
    const int* src = ei;
    const int* dst = ei + E;

    char* ws = (char*)d_ws;
    size_t off = 0;
    auto alloc = [&](size_t bytes) {
        char* p = ws + off;
        off += (bytes + 255) & ~(size_t)255;
        return p;
    };
    int*   rp   = (int*)alloc((size_t)(N + 1) * 4);
    float* dinv = (float*)alloc((size_t)N * 4);
    int NB = (N + 255) / 256;  // 196 <= 256: single-block scan2 is valid
    int* part = (int*)alloc((size_t)NB * 4);
    int* boff = (int*)alloc((size_t)NB * 4);
    int* rank = (int*)alloc((size_t)E * 4);
    int* off8 = (int*)alloc((size_t)8 * N * 4);
    // cnt8 and pack adjacent -> one contiguous zero-fill covers both
    char* zero_base = ws + off;
    int*  cnt8 = (int*)alloc((size_t)8 * N * 4);
    int2* pack = (int2*)alloc(((size_t)E + 8 * (size_t)N) * 8);  // padded CSR (x8 lists)
    size_t zero_bytes = (size_t)((char*)(pack + E + 8 * (size_t)N) - zero_base);
    int n4 = (int)((zero_bytes + 15) / 16);
    float* h1 = (float*)alloc((size_t)N * D * 4);
    float* h2 = (float*)alloc((size_t)N * D * 4);

    float* mu = (float*)d_out;
    float* lv = (float*)d_out + (size_t)N * D;

    int EB = (E + 255) / 256;
    k_zero4<<<(n4 + 255) / 256, 256, 0, stream>>>((float4*)zero_base, n4);
    k_deg  <<<EB, 256, 0, stream>>>(dst, cnt8, rank, N, E);
    k_scan1<<<NB, 256, 0, stream>>>(cnt8, part, N);
    k_scan2<<<1, 256, 0, stream>>>(part, boff, NB);
    k_scan3<<<NB, 256, 0, stream>>>(cnt8, boff, rp, off8, dinv, N);
    k_fill <<<EB, 256, 0, stream>>>(src, dst, rank, off8, dinv, pack, N, E);

    int FB = (N + 15) / 16;   // 16 nodes per 256-thread block
    // agg(x)@W == agg(x@W) by linearity; mu/logvar share the last aggregation.
    k_fused<0><<<FB, 256, 0, stream>>>(x0, rp, (const int*)pack, dinv, W1, b1, h1, N);
    k_fused<0><<<FB, 256, 0, stream>>>(h1, rp, (const int*)pack, dinv, W2, b2, h2, N);
    k_fused<1><<<FB, 256, 0, stream>>>(h2, rp, (const int*)pack, dinv, Wsc, bs, h1, N);
    k_fused_dual<<<FB, 256, 0, stream>>>(h1, rp, (const int*)pack, dinv,
                                         Wmu, bmu, Wlv, blv, mu, lv, N);
}